// Round 1
// baseline (986.758 us; speedup 1.0000x reference)
//
#include <hip/hip_runtime.h>
#include <cstdint>
#include <cstddef>

typedef unsigned short ushort_t;
typedef __bf16 bf16x8 __attribute__((ext_vector_type(8)));
typedef float f32x4 __attribute__((ext_vector_type(4)));
typedef unsigned short u16x8 __attribute__((ext_vector_type(8)));
typedef short s16x8 __attribute__((ext_vector_type(8)));

__device__ __forceinline__ ushort_t f2bf(float f) {
    unsigned u = __builtin_bit_cast(unsigned, f);
    unsigned r = (u + 0x7FFFu + ((u >> 16) & 1u)) >> 16;
    return (ushort_t)r;
}
__device__ __forceinline__ float bf2f(ushort_t h) {
    unsigned u = ((unsigned)h) << 16;
    return __builtin_bit_cast(float, u);
}

// ---------------------------------------------------------------------------
// Kernel A: Hilbert -> unit-phasor z, one block per (b,c) row.
// analytic = ifft(fft(x)*h);  z = analytic/|analytic|.
// ifft(Y) = conj(fft(conj(Y)))/N ; scale cancels in z. Both passes use the
// same forward radix-4 DIT (bit-reversed input -> natural output).
// ---------------------------------------------------------------------------
#define FFT_N 2048
__device__ __forceinline__ int PADi(int i) { return i + (i >> 4); }

__device__ __forceinline__ void fft_dit_2048(float2* c, const float2* tw, int tid) {
#pragma unroll
    for (int s = 1; s <= 9; s += 2) {   // combined radix-4 (stages s, s+1)
        __syncthreads();
        const int q = 1 << (s - 1);
#pragma unroll
        for (int kk = 0; kk < 2; ++kk) {
            int k = tid + kk * 256;     // 512 butterflies
            int p = k & (q - 1);
            int g = k >> (s - 1);
            int i0 = (g << (s + 1)) + p;
            float2 a  = c[PADi(i0)];
            float2 bb = c[PADi(i0 + q)];
            float2 cc = c[PADi(i0 + 2 * q)];
            float2 dd = c[PADi(i0 + 3 * q)];
            float2 w1 = tw[PADi(p << (11 - s))];
            float2 w2 = tw[PADi(p << (10 - s))];
            float w3r = w1.x * w2.x - w1.y * w2.y;
            float w3i = w1.x * w2.y + w1.y * w2.x;
            float t1r = w1.x * bb.x - w1.y * bb.y, t1i = w1.x * bb.y + w1.y * bb.x;
            float t2r = w2.x * cc.x - w2.y * cc.y, t2i = w2.x * cc.y + w2.y * cc.x;
            float t3r = w3r * dd.x - w3i * dd.y,  t3i = w3r * dd.y + w3i * dd.x;
            float sAr = a.x + t1r, sAi = a.y + t1i;
            float sBr = a.x - t1r, sBi = a.y - t1i;
            float sCr = t2r + t3r, sCi = t2i + t3i;
            float uR  = t2r - t3r, uI  = t2i - t3i;
            c[PADi(i0)]         = make_float2(sAr + sCr, sAi + sCi);
            c[PADi(i0 + q)]     = make_float2(sBr + uI,  sBi - uR);   // -i*(t2-t3)
            c[PADi(i0 + 2 * q)] = make_float2(sAr - sCr, sAi - sCi);
            c[PADi(i0 + 3 * q)] = make_float2(sBr - uI,  sBi + uR);
        }
    }
    __syncthreads();
#pragma unroll
    for (int kk = 0; kk < 4; ++kk) {    // final radix-2 stage (s=11)
        int k = tid + kk * 256;         // 1024 butterflies
        float2 w = tw[PADi(k)];
        float2 a = c[PADi(k)];
        float2 b = c[PADi(k + 1024)];
        float tr = w.x * b.x - w.y * b.y;
        float ti = w.x * b.y + w.y * b.x;
        c[PADi(k)]        = make_float2(a.x + tr, a.y + ti);
        c[PADi(k + 1024)] = make_float2(a.x - tr, a.y - ti);
    }
}

__global__ __launch_bounds__(256) void hilbert_kernel(
    const float* __restrict__ x, ushort_t* __restrict__ zre,
    ushort_t* __restrict__ zim, int b0)
{
    __shared__ float2 c[2176];
    __shared__ float2 tw[1088];
    const int tid = threadIdx.x;
    const int row = blockIdx.x;                       // local row in chunk
    const size_t grow = (size_t)(b0 * 128) + row;     // global row
    const float* xr = x + grow * FFT_N;

    for (int k = tid; k < 1024; k += 256) {
        float ang = -3.14159265358979323846f * (float)k / 1024.0f;
        float s, co;
        __sincosf(ang, &s, &co);
        tw[PADi(k)] = make_float2(co, s);
    }
    for (int i = tid; i < FFT_N; i += 256) {
        int j = __brev((unsigned)i) >> 21;
        c[PADi(j)] = make_float2(xr[i], 0.0f);
    }
    fft_dit_2048(c, tw, tid);          // X = fft(x), natural order
    __syncthreads();
    for (int i = tid; i < FFT_N; i += 256) {   // Y = X*h, then conj(Y)
        float f = (i == 0 || i == 1024) ? 1.0f : (i < 1024 ? 2.0f : 0.0f);
        float2 v = c[PADi(i)];
        c[PADi(i)] = make_float2(v.x * f, -v.y * f);
    }
    __syncthreads();
    for (int i = tid; i < FFT_N; i += 256) {   // bit-reverse permute in place
        int j = __brev((unsigned)i) >> 21;
        if (i < j) {
            float2 a = c[PADi(i)], b = c[PADi(j)];
            c[PADi(i)] = b;
            c[PADi(j)] = a;
        }
    }
    fft_dit_2048(c, tw, tid);          // w = fft(conj(Y)); analytic = conj(w)/N
    __syncthreads();
    for (int n = tid; n < FFT_N; n += 256) {
        float2 w = c[PADi(n)];
        float m2 = w.x * w.x + w.y * w.y;
        float zr, zi;
        if (m2 < 1e-30f) { zr = 1.0f; zi = 0.0f; }   // angle(0)=0 -> z=1
        else { float inv = rsqrtf(m2); zr = w.x * inv; zi = -w.y * inv; }
        zre[(size_t)row * FFT_N + n] = f2bf(zr);
        zim[(size_t)row * FFT_N + n] = f2bf(zi);
    }
}

// ---------------------------------------------------------------------------
// Kernel B: conn[b,i,j] = |sum_t z_i conj(z_j)| / T, diag zeroed.
// Re(G)=R R^T + I I^T ; Im(G)=I R^T - R I^T ; bf16 MFMA, fp32 accum.
// 2 blocks/batch (64 rows each), 8 waves, K-tiles of 64, XOR-swizzled LDS.
// ---------------------------------------------------------------------------
__global__ __launch_bounds__(512) void gram_kernel(
    const ushort_t* __restrict__ zre, const ushort_t* __restrict__ zim,
    float* __restrict__ out, int b0)
{
    __shared__ __align__(16) char sm[65536];          // 2 x (re 16KB + im 16KB)
    const int tid = threadIdx.x;
    const int bl = blockIdx.x;
    const int b_local = bl >> 1;
    const int half = bl & 1;
    const int b = b0 + b_local;
    const int lane = tid & 63;
    const int w = tid >> 6;
    const int wm = w >> 2, wn = w & 3;                // 2x4 wave grid, 32x32 tiles
    const size_t zbase = (size_t)b_local * 128 * FFT_N;

    f32x4 accR[2][2], accI[2][2];
    const f32x4 zero4 = {0.f, 0.f, 0.f, 0.f};
#pragma unroll
    for (int mi = 0; mi < 2; ++mi)
#pragma unroll
        for (int nj = 0; nj < 2; ++nj) { accR[mi][nj] = zero4; accI[mi][nj] = zero4; }

    auto stage = [&](int kc, int buf) {
        const int kcol = kc * 64;
#pragma unroll
        for (int it = 0; it < 4; ++it) {
            int cid = it * 512 + tid;                 // 2048 x 16B = 32KB tile
            int p = cid >> 10;                        // plane (re/im)
            int rem = cid & 1023;
            int r = rem >> 3;                         // channel row 0..127
            int g = rem & 7;                          // 16B group in 128B row
            const ushort_t* src = (p ? zim : zre) + zbase + (size_t)r * FFT_N + kcol + g * 8;
            u16x8 v = *(const u16x8*)src;
            int off = (buf << 15) | (p << 14) | (r << 7) | (g << 4);
            off ^= ((r & 7) << 4);                    // bank swizzle
            *(u16x8*)(sm + off) = v;
        }
    };

    stage(0, 0);
    __syncthreads();
    int buf = 0;
    const int mBase = half * 64 + wm * 32;
    const int nBase = wn * 32;
    for (int kc = 0; kc < 32; ++kc) {
        if (kc + 1 < 32) stage(kc + 1, buf ^ 1);
        const char* base = sm + (buf << 15);
#pragma unroll
        for (int ks = 0; ks < 2; ++ks) {
            bf16x8 aRe[2], aIm[2], bRe[2], bIm[2], nRe[2];
#pragma unroll
            for (int mi = 0; mi < 2; ++mi) {
                int R = mBase + mi * 16 + (lane & 15);
                int off = (R << 7) | (ks << 6) | ((lane >> 4) << 4);
                off ^= ((R & 7) << 4);
                aRe[mi] = *(const bf16x8*)(base + off);
                aIm[mi] = *(const bf16x8*)(base + 16384 + off);
                s16x8 t = __builtin_bit_cast(s16x8, aRe[mi]);
                t ^= (short)0x8000;                   // -Re for imag part
                nRe[mi] = __builtin_bit_cast(bf16x8, t);
            }
#pragma unroll
            for (int nj = 0; nj < 2; ++nj) {
                int C = nBase + nj * 16 + (lane & 15);
                int off = (C << 7) | (ks << 6) | ((lane >> 4) << 4);
                off ^= ((C & 7) << 4);
                bRe[nj] = *(const bf16x8*)(base + off);
                bIm[nj] = *(const bf16x8*)(base + 16384 + off);
            }
#pragma unroll
            for (int mi = 0; mi < 2; ++mi)
#pragma unroll
                for (int nj = 0; nj < 2; ++nj) {
                    accR[mi][nj] = __builtin_amdgcn_mfma_f32_16x16x32_bf16(aRe[mi], bRe[nj], accR[mi][nj], 0, 0, 0);
                    accR[mi][nj] = __builtin_amdgcn_mfma_f32_16x16x32_bf16(aIm[mi], bIm[nj], accR[mi][nj], 0, 0, 0);
                    accI[mi][nj] = __builtin_amdgcn_mfma_f32_16x16x32_bf16(aIm[mi], bRe[nj], accI[mi][nj], 0, 0, 0);
                    accI[mi][nj] = __builtin_amdgcn_mfma_f32_16x16x32_bf16(nRe[mi], bIm[nj], accI[mi][nj], 0, 0, 0);
                }
        }
        __syncthreads();
        buf ^= 1;
    }
    float* ob = out + (size_t)b * 16384;
#pragma unroll
    for (int mi = 0; mi < 2; ++mi)
#pragma unroll
        for (int nj = 0; nj < 2; ++nj)
#pragma unroll
            for (int r = 0; r < 4; ++r) {
                int i = mBase + mi * 16 + (lane >> 4) * 4 + r;
                int j = nBase + nj * 16 + (lane & 15);
                float re = accR[mi][nj][r], im = accI[mi][nj][r];
                float v = sqrtf(re * re + im * im) * (1.0f / 2048.0f);
                if (i == j) v = 0.0f;
                ob[i * 128 + j] = v;
            }
}

// ---------------------------------------------------------------------------
// Kernel C: nodeW1 = emb @ W1   (shared across batch)
// ---------------------------------------------------------------------------
__global__ __launch_bounds__(256) void nodew1_kernel(
    const float* __restrict__ emb, const float* __restrict__ W1,
    float* __restrict__ nodeW1)
{
    int tid = threadIdx.x;
    for (int idx = tid; idx < 128 * 128; idx += 256) {
        int i = idx >> 7, f = idx & 127;
        float acc = 0.0f;
        for (int e = 0; e < 64; ++e) acc += emb[i * 64 + e] * W1[e * 128 + f];
        nodeW1[idx] = acc;
    }
}

// ---------------------------------------------------------------------------
// Kernel D: h1 = relu(conn@nodeW1 + b1); h2 = conn@(h1@W2) + b2  (per batch)
// ---------------------------------------------------------------------------
__global__ __launch_bounds__(256) void gcn_kernel(
    const float* __restrict__ conn, const float* __restrict__ nodeW1,
    const float* __restrict__ W2, const float* __restrict__ b1,
    const float* __restrict__ b2, float* __restrict__ h2out)
{
    __shared__ __align__(16) ushort_t h1bf[128 * 128];   // 32KB
    __shared__ float t2[128 * 64];                       // 32KB
    int tid = threadIdx.x;
    int b = blockIdx.x;
    const float* cb = conn + (size_t)b * 16384;
    for (int idx = tid; idx < 16384; idx += 256) {
        int i = idx >> 7, f = idx & 127;
        float acc = b1[f];
        const float* cr = cb + i * 128;
        for (int k = 0; k < 128; ++k) acc += cr[k] * nodeW1[k * 128 + f];
        h1bf[idx] = f2bf(fmaxf(acc, 0.0f));
    }
    __syncthreads();
    for (int idx = tid; idx < 8192; idx += 256) {
        int i = idx >> 6, f = idx & 63;
        float acc = 0.0f;
        const ushort_t* hr = h1bf + i * 128;
        for (int k = 0; k < 128; ++k) acc += bf2f(hr[k]) * W2[k * 64 + f];
        t2[idx] = acc;
    }
    __syncthreads();
    for (int idx = tid; idx < 8192; idx += 256) {
        int i = idx >> 6, f = idx & 63;
        float acc = b2[f];
        const float* cr = cb + i * 128;
        for (int k = 0; k < 128; ++k) acc += cr[k] * t2[k * 64 + f];
        h2out[(size_t)b * 8192 + idx] = acc;
    }
}

// ---------------------------------------------------------------------------
// Kernel E: q,k,v = h2@W*, online-softmax attention (H=8,d=8), gf = o@Wo+bo
// ---------------------------------------------------------------------------
__global__ __launch_bounds__(256) void attn_kernel(
    const float* __restrict__ h2, const float* __restrict__ Wq,
    const float* __restrict__ bq, const float* __restrict__ Wk,
    const float* __restrict__ bk, const float* __restrict__ Wv,
    const float* __restrict__ bv, const float* __restrict__ Wo,
    const float* __restrict__ bo, float* __restrict__ gf)
{
    __shared__ __align__(16) ushort_t kbf[128 * 64];     // 16KB
    __shared__ __align__(16) ushort_t vbf[128 * 64];     // 16KB
    __shared__ float osm[128 * 64];                      // 32KB: h2^T then o
    int tid = threadIdx.x;
    int b = blockIdx.x;
    const float* h2b = h2 + (size_t)b * 8192;

    for (int idx = tid; idx < 8192; idx += 256) {        // osm = h2^T
        int i = idx >> 6, e = idx & 63;
        osm[e * 128 + i] = h2b[idx];
    }
    __syncthreads();
    for (int idx = tid; idx < 8192; idx += 256) {        // k,v build
        int i = idx >> 6, f = idx & 63;
        float ak = bk[f], av = bv[f];
        for (int e = 0; e < 64; ++e) {
            float h = osm[e * 128 + i];                  // broadcast read
            ak += h * Wk[e * 64 + f];
            av += h * Wv[e * 64 + f];
        }
        kbf[idx] = f2bf(ak);
        vbf[idx] = f2bf(av);
    }
    float q[4][8];                                       // q build (uses h2^T)
#pragma unroll
    for (int p = 0; p < 4; ++p) {
        int task = tid + (p << 8);
        int i = task & 127;
        int hb8 = (task >> 7) * 8;
#pragma unroll
        for (int d = 0; d < 8; ++d) q[p][d] = bq[hb8 + d];
        for (int e = 0; e < 64; ++e) {
            float hv = osm[e * 128 + i];
            const float* wr = Wq + e * 64 + hb8;
#pragma unroll
            for (int d = 0; d < 8; ++d) q[p][d] += hv * wr[d];
        }
    }
    __syncthreads();                                     // h2^T dead; osm -> o
    const float rs = 0.35355339059327373f;               // 8^-0.5
#pragma unroll
    for (int p = 0; p < 4; ++p) {
        int task = tid + (p << 8);
        int i = task & 127;
        int hb8 = (task >> 7) * 8;
        float m = -3.0e38f, l = 0.0f;
        float o[8] = {0, 0, 0, 0, 0, 0, 0, 0};
        for (int j = 0; j < 128; ++j) {
            u16x8 kv = *(const u16x8*)(kbf + j * 64 + hb8);
            float s = 0.0f;
#pragma unroll
            for (int d = 0; d < 8; ++d) s += q[p][d] * bf2f(kv[d]);
            s *= rs;
            float mn = fmaxf(m, s);
            float cold = __expf(m - mn);
            float ce = __expf(s - mn);
            l = l * cold + ce;
            u16x8 vv = *(const u16x8*)(vbf + j * 64 + hb8);
#pragma unroll
            for (int d = 0; d < 8; ++d) o[d] = o[d] * cold + ce * bf2f(vv[d]);
            m = mn;
        }
        float inv = 1.0f / l;
#pragma unroll
        for (int d = 0; d < 8; ++d) osm[i * 64 + hb8 + d] = o[d] * inv;
    }
    __syncthreads();
    for (int idx = tid; idx < 8192; idx += 256) {        // gf = o@Wo + bo
        int i = idx >> 6, f = idx & 63;
        float acc = bo[f];
        const float* orow = osm + i * 64;
        for (int e = 0; e < 64; ++e) acc += orow[e] * Wo[e * 64 + f];
        gf[(size_t)b * 8192 + idx] = acc;
    }
}

// ---------------------------------------------------------------------------
extern "C" void kernel_launch(void* const* d_in, const int* in_sizes, int n_in,
                              void* d_out, int out_size, void* d_ws, size_t ws_size,
                              hipStream_t stream)
{
    (void)in_sizes; (void)n_in; (void)out_size;
    const float* x   = (const float*)d_in[0];
    const float* emb = (const float*)d_in[1];
    const float* W1  = (const float*)d_in[2];
    const float* b1  = (const float*)d_in[3];
    const float* W2  = (const float*)d_in[4];
    const float* b2  = (const float*)d_in[5];
    const float* Wq  = (const float*)d_in[6];
    const float* bq  = (const float*)d_in[7];
    const float* Wk  = (const float*)d_in[8];
    const float* bk  = (const float*)d_in[9];
    const float* Wv  = (const float*)d_in[10];
    const float* bv  = (const float*)d_in[11];
    const float* Wo  = (const float*)d_in[12];
    const float* bo  = (const float*)d_in[13];

    float* out  = (float*)d_out;
    float* conn = out;                    // 128*128*128
    float* gf   = out + 2097152;          // 128*128*64
    float* h2   = out + 3145728;          // 128*128*64

    char* ws = (char*)d_ws;
    float* nodeW1 = (float*)ws;           // 64KB
    char* zbase = ws + 65536;
    size_t avail = (ws_size > 65536) ? (ws_size - 65536) : 0;
    int nb = (int)(avail / 1048576);      // 1MB of z (re+im bf16) per batch
    if (nb < 1) nb = 1;
    if (nb > 128) nb = 128;

    for (int b0 = 0; b0 < 128; b0 += nb) {
        int cur = (nb < 128 - b0) ? nb : (128 - b0);
        ushort_t* zre = (ushort_t*)zbase;
        ushort_t* zim = zre + (size_t)cur * 128 * FFT_N;
        hilbert_kernel<<<cur * 128, 256, 0, stream>>>(x, zre, zim, b0);
        gram_kernel<<<cur * 2, 512, 0, stream>>>(zre, zim, conn, b0);
    }
    nodew1_kernel<<<1, 256, 0, stream>>>(emb, W1, nodeW1);
    gcn_kernel<<<128, 256, 0, stream>>>(conn, nodeW1, W2, b1, b2, h2);
    attn_kernel<<<128, 256, 0, stream>>>(h2, Wq, bq, Wk, bk, Wv, bv, Wo, bo, gf);
}

// Round 2
// 731.925 us; speedup vs baseline: 1.3482x; 1.3482x over previous
//
#include <hip/hip_runtime.h>
#include <cstdint>
#include <cstddef>

typedef unsigned short ushort_t;
typedef __bf16 bf16x8 __attribute__((ext_vector_type(8)));
typedef float f32x4 __attribute__((ext_vector_type(4)));
typedef unsigned short u16x8 __attribute__((ext_vector_type(8)));
typedef short s16x8 __attribute__((ext_vector_type(8)));

__device__ __forceinline__ ushort_t f2bf(float f) {
    unsigned u = __builtin_bit_cast(unsigned, f);
    unsigned r = (u + 0x7FFFu + ((u >> 16) & 1u)) >> 16;
    return (ushort_t)r;
}
__device__ __forceinline__ float bf2f(ushort_t h) {
    unsigned u = ((unsigned)h) << 16;
    return __builtin_bit_cast(float, u);
}

// ---------------------------------------------------------------------------
// Kernel A: Hilbert -> unit-phasor z, one block per (b,c) row.
// analytic = ifft(fft(x)*h);  z = analytic/|analytic|.
// ifft(Y) = conj(fft(conj(Y)))/N ; scale cancels in z. Both passes use the
// same forward radix-4 DIT (bit-reversed input -> natural output).
// ---------------------------------------------------------------------------
#define FFT_N 2048
__device__ __forceinline__ int PADi(int i) { return i + (i >> 4); }

__device__ __forceinline__ void fft_dit_2048(float2* c, const float2* tw, int tid) {
#pragma unroll
    for (int s = 1; s <= 9; s += 2) {   // combined radix-4 (stages s, s+1)
        __syncthreads();
        const int q = 1 << (s - 1);
#pragma unroll
        for (int kk = 0; kk < 2; ++kk) {
            int k = tid + kk * 256;     // 512 butterflies
            int p = k & (q - 1);
            int g = k >> (s - 1);
            int i0 = (g << (s + 1)) + p;
            float2 a  = c[PADi(i0)];
            float2 bb = c[PADi(i0 + q)];
            float2 cc = c[PADi(i0 + 2 * q)];
            float2 dd = c[PADi(i0 + 3 * q)];
            float2 w1 = tw[PADi(p << (11 - s))];
            float2 w2 = tw[PADi(p << (10 - s))];
            float w3r = w1.x * w2.x - w1.y * w2.y;
            float w3i = w1.x * w2.y + w1.y * w2.x;
            float t1r = w1.x * bb.x - w1.y * bb.y, t1i = w1.x * bb.y + w1.y * bb.x;
            float t2r = w2.x * cc.x - w2.y * cc.y, t2i = w2.x * cc.y + w2.y * cc.x;
            float t3r = w3r * dd.x - w3i * dd.y,  t3i = w3r * dd.y + w3i * dd.x;
            float sAr = a.x + t1r, sAi = a.y + t1i;
            float sBr = a.x - t1r, sBi = a.y - t1i;
            float sCr = t2r + t3r, sCi = t2i + t3i;
            float uR  = t2r - t3r, uI  = t2i - t3i;
            c[PADi(i0)]         = make_float2(sAr + sCr, sAi + sCi);
            c[PADi(i0 + q)]     = make_float2(sBr + uI,  sBi - uR);   // -i*(t2-t3)
            c[PADi(i0 + 2 * q)] = make_float2(sAr - sCr, sAi - sCi);
            c[PADi(i0 + 3 * q)] = make_float2(sBr - uI,  sBi + uR);
        }
    }
    __syncthreads();
#pragma unroll
    for (int kk = 0; kk < 4; ++kk) {    // final radix-2 stage (s=11)
        int k = tid + kk * 256;         // 1024 butterflies
        float2 w = tw[PADi(k)];
        float2 a = c[PADi(k)];
        float2 b = c[PADi(k + 1024)];
        float tr = w.x * b.x - w.y * b.y;
        float ti = w.x * b.y + w.y * b.x;
        c[PADi(k)]        = make_float2(a.x + tr, a.y + ti);
        c[PADi(k + 1024)] = make_float2(a.x - tr, a.y - ti);
    }
}

__global__ __launch_bounds__(256) void hilbert_kernel(
    const float* __restrict__ x, ushort_t* __restrict__ zre,
    ushort_t* __restrict__ zim, int b0)
{
    __shared__ float2 c[2176];
    __shared__ float2 tw[1088];
    const int tid = threadIdx.x;
    const int row = blockIdx.x;                       // local row in chunk
    const size_t grow = (size_t)(b0 * 128) + row;     // global row
    const float* xr = x + grow * FFT_N;

    for (int k = tid; k < 1024; k += 256) {
        float ang = -3.14159265358979323846f * (float)k / 1024.0f;
        float s, co;
        __sincosf(ang, &s, &co);
        tw[PADi(k)] = make_float2(co, s);
    }
    for (int i = tid; i < FFT_N; i += 256) {
        int j = __brev((unsigned)i) >> 21;
        c[PADi(j)] = make_float2(xr[i], 0.0f);
    }
    fft_dit_2048(c, tw, tid);          // X = fft(x), natural order
    __syncthreads();
    for (int i = tid; i < FFT_N; i += 256) {   // Y = X*h, then conj(Y)
        float f = (i == 0 || i == 1024) ? 1.0f : (i < 1024 ? 2.0f : 0.0f);
        float2 v = c[PADi(i)];
        c[PADi(i)] = make_float2(v.x * f, -v.y * f);
    }
    __syncthreads();
    for (int i = tid; i < FFT_N; i += 256) {   // bit-reverse permute in place
        int j = __brev((unsigned)i) >> 21;
        if (i < j) {
            float2 a = c[PADi(i)], b = c[PADi(j)];
            c[PADi(i)] = b;
            c[PADi(j)] = a;
        }
    }
    fft_dit_2048(c, tw, tid);          // w = fft(conj(Y)); analytic = conj(w)/N
    __syncthreads();
    for (int n = tid; n < FFT_N; n += 256) {
        float2 w = c[PADi(n)];
        float m2 = w.x * w.x + w.y * w.y;
        float zr, zi;
        if (m2 < 1e-30f) { zr = 1.0f; zi = 0.0f; }   // angle(0)=0 -> z=1
        else { float inv = rsqrtf(m2); zr = w.x * inv; zi = -w.y * inv; }
        zre[(size_t)row * FFT_N + n] = f2bf(zr);
        zim[(size_t)row * FFT_N + n] = f2bf(zi);
    }
}

// ---------------------------------------------------------------------------
// Kernel B: conn[b,i,j] = |sum_t z_i conj(z_j)| / T, diag zeroed.
// Re(G)=R R^T + I I^T ; Im(G)=I R^T - R I^T ; bf16 MFMA, fp32 accum.
// 2 blocks/batch (64 rows each), 8 waves, K-tiles of 64, XOR-swizzled LDS.
// ---------------------------------------------------------------------------
__global__ __launch_bounds__(512) void gram_kernel(
    const ushort_t* __restrict__ zre, const ushort_t* __restrict__ zim,
    float* __restrict__ out, int b0)
{
    __shared__ __align__(16) char sm[65536];          // 2 x (re 16KB + im 16KB)
    const int tid = threadIdx.x;
    const int bl = blockIdx.x;
    const int b_local = bl >> 1;
    const int half = bl & 1;
    const int b = b0 + b_local;
    const int lane = tid & 63;
    const int w = tid >> 6;
    const int wm = w >> 2, wn = w & 3;                // 2x4 wave grid, 32x32 tiles
    const size_t zbase = (size_t)b_local * 128 * FFT_N;

    f32x4 accR[2][2], accI[2][2];
    const f32x4 zero4 = {0.f, 0.f, 0.f, 0.f};
#pragma unroll
    for (int mi = 0; mi < 2; ++mi)
#pragma unroll
        for (int nj = 0; nj < 2; ++nj) { accR[mi][nj] = zero4; accI[mi][nj] = zero4; }

    auto stage = [&](int kc, int buf) {
        const int kcol = kc * 64;
#pragma unroll
        for (int it = 0; it < 4; ++it) {
            int cid = it * 512 + tid;                 // 2048 x 16B = 32KB tile
            int p = cid >> 10;                        // plane (re/im)
            int rem = cid & 1023;
            int r = rem >> 3;                         // channel row 0..127
            int g = rem & 7;                          // 16B group in 128B row
            const ushort_t* src = (p ? zim : zre) + zbase + (size_t)r * FFT_N + kcol + g * 8;
            u16x8 v = *(const u16x8*)src;
            int off = (buf << 15) | (p << 14) | (r << 7) | (g << 4);
            off ^= ((r & 7) << 4);                    // bank swizzle
            *(u16x8*)(sm + off) = v;
        }
    };

    stage(0, 0);
    __syncthreads();
    int buf = 0;
    const int mBase = half * 64 + wm * 32;
    const int nBase = wn * 32;
    for (int kc = 0; kc < 32; ++kc) {
        if (kc + 1 < 32) stage(kc + 1, buf ^ 1);
        const char* base = sm + (buf << 15);
#pragma unroll
        for (int ks = 0; ks < 2; ++ks) {
            bf16x8 aRe[2], aIm[2], bRe[2], bIm[2], nRe[2];
#pragma unroll
            for (int mi = 0; mi < 2; ++mi) {
                int R = mBase + mi * 16 + (lane & 15);
                int off = (R << 7) | (ks << 6) | ((lane >> 4) << 4);
                off ^= ((R & 7) << 4);
                aRe[mi] = *(const bf16x8*)(base + off);
                aIm[mi] = *(const bf16x8*)(base + 16384 + off);
                s16x8 t = __builtin_bit_cast(s16x8, aRe[mi]);
                t ^= (short)0x8000;                   // -Re for imag part
                nRe[mi] = __builtin_bit_cast(bf16x8, t);
            }
#pragma unroll
            for (int nj = 0; nj < 2; ++nj) {
                int C = nBase + nj * 16 + (lane & 15);
                int off = (C << 7) | (ks << 6) | ((lane >> 4) << 4);
                off ^= ((C & 7) << 4);
                bRe[nj] = *(const bf16x8*)(base + off);
                bIm[nj] = *(const bf16x8*)(base + 16384 + off);
            }
#pragma unroll
            for (int mi = 0; mi < 2; ++mi)
#pragma unroll
                for (int nj = 0; nj < 2; ++nj) {
                    accR[mi][nj] = __builtin_amdgcn_mfma_f32_16x16x32_bf16(aRe[mi], bRe[nj], accR[mi][nj], 0, 0, 0);
                    accR[mi][nj] = __builtin_amdgcn_mfma_f32_16x16x32_bf16(aIm[mi], bIm[nj], accR[mi][nj], 0, 0, 0);
                    accI[mi][nj] = __builtin_amdgcn_mfma_f32_16x16x32_bf16(aIm[mi], bRe[nj], accI[mi][nj], 0, 0, 0);
                    accI[mi][nj] = __builtin_amdgcn_mfma_f32_16x16x32_bf16(nRe[mi], bIm[nj], accI[mi][nj], 0, 0, 0);
                }
        }
        __syncthreads();
        buf ^= 1;
    }
    float* ob = out + (size_t)b * 16384;
#pragma unroll
    for (int mi = 0; mi < 2; ++mi)
#pragma unroll
        for (int nj = 0; nj < 2; ++nj)
#pragma unroll
            for (int r = 0; r < 4; ++r) {
                int i = mBase + mi * 16 + (lane >> 4) * 4 + r;
                int j = nBase + nj * 16 + (lane & 15);
                float re = accR[mi][nj][r], im = accI[mi][nj][r];
                float v = sqrtf(re * re + im * im) * (1.0f / 2048.0f);
                if (i == j) v = 0.0f;
                ob[i * 128 + j] = v;
            }
}

// ---------------------------------------------------------------------------
// Kernel C: nodeW1 = emb @ W1   (shared across batch)
// ---------------------------------------------------------------------------
__global__ __launch_bounds__(256) void nodew1_kernel(
    const float* __restrict__ emb, const float* __restrict__ W1,
    float* __restrict__ nodeW1)
{
    int tid = threadIdx.x;
    for (int idx = tid; idx < 128 * 128; idx += 256) {
        int i = idx >> 7, f = idx & 127;
        float acc = 0.0f;
        for (int e = 0; e < 64; ++e) acc += emb[i * 64 + e] * W1[e * 128 + f];
        nodeW1[idx] = acc;
    }
}

// ---------------------------------------------------------------------------
// Kernel D: h1 = relu(conn@nodeW1 + b1); h2 = conn@(h1@W2) + b2  (per batch)
// ---------------------------------------------------------------------------
__global__ __launch_bounds__(256) void gcn_kernel(
    const float* __restrict__ conn, const float* __restrict__ nodeW1,
    const float* __restrict__ W2, const float* __restrict__ b1,
    const float* __restrict__ b2, float* __restrict__ h2out)
{
    __shared__ __align__(16) ushort_t h1bf[128 * 128];   // 32KB
    __shared__ float t2[128 * 64];                       // 32KB
    int tid = threadIdx.x;
    int b = blockIdx.x;
    const float* cb = conn + (size_t)b * 16384;
    for (int idx = tid; idx < 16384; idx += 256) {
        int i = idx >> 7, f = idx & 127;
        float acc = b1[f];
        const float* cr = cb + i * 128;
        for (int k = 0; k < 128; ++k) acc += cr[k] * nodeW1[k * 128 + f];
        h1bf[idx] = f2bf(fmaxf(acc, 0.0f));
    }
    __syncthreads();
    for (int idx = tid; idx < 8192; idx += 256) {
        int i = idx >> 6, f = idx & 63;
        float acc = 0.0f;
        const ushort_t* hr = h1bf + i * 128;
        for (int k = 0; k < 128; ++k) acc += bf2f(hr[k]) * W2[k * 64 + f];
        t2[idx] = acc;
    }
    __syncthreads();
    for (int idx = tid; idx < 8192; idx += 256) {
        int i = idx >> 6, f = idx & 63;
        float acc = b2[f];
        const float* cr = cb + i * 128;
        for (int k = 0; k < 128; ++k) acc += cr[k] * t2[k * 64 + f];
        h2out[(size_t)b * 8192 + idx] = acc;
    }
}

// ---------------------------------------------------------------------------
// Kernel E (rewritten): 2 blocks per batch, 64 query rows each.
// Sequential per-thread tasks, ~40 VGPR footprint, no spills.
// ---------------------------------------------------------------------------
__global__ __launch_bounds__(256) void attn_kernel(
    const float* __restrict__ h2, const float* __restrict__ Wq,
    const float* __restrict__ bq, const float* __restrict__ Wk,
    const float* __restrict__ bk, const float* __restrict__ Wv,
    const float* __restrict__ bv, const float* __restrict__ Wo,
    const float* __restrict__ bo, float* __restrict__ gf)
{
    __shared__ float h2T[64 * 130];                      // h2^T padded (33.3KB)
    __shared__ __align__(16) ushort_t kbf[128 * 64];     // 16KB
    __shared__ __align__(16) ushort_t vbf[128 * 64];     // 16KB
    __shared__ float osm[64 * 64];                       // 16KB
    const int tid = threadIdx.x;
    const int b = blockIdx.x >> 1;
    const int half = blockIdx.x & 1;
    const float* h2b = h2 + (size_t)b * 8192;

    for (int idx = tid; idx < 8192; idx += 256) {        // h2T[e][i] = h2[i][e]
        int i = idx >> 6, e = idx & 63;
        h2T[e * 130 + i] = h2b[idx];
    }
    __syncthreads();
    for (int idx = tid; idx < 8192; idx += 256) {        // k,v for ALL 128 keys
        int i = idx >> 6, f = idx & 63;                  // wave: i uniform, f=lane
        float ak = bk[f], av = bv[f];
        for (int e = 0; e < 64; ++e) {
            float h = h2T[e * 130 + i];                  // broadcast
            ak += h * Wk[e * 64 + f];                    // coalesced, L1-hit
            av += h * Wv[e * 64 + f];
        }
        kbf[idx] = f2bf(ak);
        vbf[idx] = f2bf(av);
    }
    __syncthreads();
    const float rs = 0.35355339059327373f;               // 8^-0.5
    for (int it = 0; it < 2; ++it) {                     // 512 tasks / 256 thr
        int task = tid + it * 256;
        int il = task & 63;                              // local q row (lane)
        int hb8 = (task >> 6) * 8;                       // head*8, wave-uniform
        int i = half * 64 + il;
        float q[8];
#pragma unroll
        for (int d = 0; d < 8; ++d) q[d] = bq[hb8 + d];
        for (int e = 0; e < 64; ++e) {
            float hv = h2T[e * 130 + i];                 // consecutive per lane
            const float* wr = Wq + e * 64 + hb8;         // wave-uniform
#pragma unroll
            for (int d = 0; d < 8; ++d) q[d] += hv * wr[d];
        }
        float m = -3.0e38f, l = 0.0f;
        float o[8] = {0, 0, 0, 0, 0, 0, 0, 0};
        for (int j = 0; j < 128; ++j) {
            u16x8 kv = *(const u16x8*)(kbf + j * 64 + hb8);  // broadcast 16B
            float s = 0.0f;
#pragma unroll
            for (int d = 0; d < 8; ++d) s += q[d] * bf2f(kv[d]);
            s *= rs;
            float mn = fmaxf(m, s);
            float cold = __expf(m - mn);
            float ce = __expf(s - mn);
            l = l * cold + ce;
            u16x8 vv = *(const u16x8*)(vbf + j * 64 + hb8);
#pragma unroll
            for (int d = 0; d < 8; ++d) o[d] = o[d] * cold + ce * bf2f(vv[d]);
            m = mn;
        }
        float inv = 1.0f / l;
#pragma unroll
        for (int d = 0; d < 8; ++d) osm[il * 64 + hb8 + d] = o[d] * inv;
    }
    __syncthreads();
    for (int idx = tid; idx < 4096; idx += 256) {        // gf = o@Wo + bo
        int il = idx >> 6, f = idx & 63;
        float acc = bo[f];
        const float* orow = osm + il * 64;               // broadcast
        for (int e = 0; e < 64; ++e) acc += orow[e] * Wo[e * 64 + f];
        gf[(size_t)b * 8192 + (size_t)(half * 64 + il) * 64 + f] = acc;
    }
}

// ---------------------------------------------------------------------------
extern "C" void kernel_launch(void* const* d_in, const int* in_sizes, int n_in,
                              void* d_out, int out_size, void* d_ws, size_t ws_size,
                              hipStream_t stream)
{
    (void)in_sizes; (void)n_in; (void)out_size;
    const float* x   = (const float*)d_in[0];
    const float* emb = (const float*)d_in[1];
    const float* W1  = (const float*)d_in[2];
    const float* b1  = (const float*)d_in[3];
    const float* W2  = (const float*)d_in[4];
    const float* b2  = (const float*)d_in[5];
    const float* Wq  = (const float*)d_in[6];
    const float* bq  = (const float*)d_in[7];
    const float* Wk  = (const float*)d_in[8];
    const float* bk  = (const float*)d_in[9];
    const float* Wv  = (const float*)d_in[10];
    const float* bv  = (const float*)d_in[11];
    const float* Wo  = (const float*)d_in[12];
    const float* bo  = (const float*)d_in[13];

    float* out  = (float*)d_out;
    float* conn = out;                    // 128*128*128
    float* gf   = out + 2097152;          // 128*128*64
    float* h2   = out + 3145728;          // 128*128*64

    char* ws = (char*)d_ws;
    float* nodeW1 = (float*)ws;           // 64KB
    char* zbase = ws + 65536;
    size_t avail = (ws_size > 65536) ? (ws_size - 65536) : 0;
    int nb = (int)(avail / 1048576);      // 1MB of z (re+im bf16) per batch
    if (nb < 1) nb = 1;
    if (nb > 128) nb = 128;

    for (int b0 = 0; b0 < 128; b0 += nb) {
        int cur = (nb < 128 - b0) ? nb : (128 - b0);
        ushort_t* zre = (ushort_t*)zbase;
        ushort_t* zim = zre + (size_t)cur * 128 * FFT_N;
        hilbert_kernel<<<cur * 128, 256, 0, stream>>>(x, zre, zim, b0);
        gram_kernel<<<cur * 2, 512, 0, stream>>>(zre, zim, conn, b0);
    }
    nodew1_kernel<<<1, 256, 0, stream>>>(emb, W1, nodeW1);
    gcn_kernel<<<128, 256, 0, stream>>>(conn, nodeW1, W2, b1, b2, h2);
    attn_kernel<<<256, 256, 0, stream>>>(h2, Wq, bq, Wk, bk, Wv, bv, Wo, bo, gf);
}

// Round 3
// 366.281 us; speedup vs baseline: 2.6940x; 1.9983x over previous
//
#include <hip/hip_runtime.h>
#include <cstdint>
#include <cstddef>

typedef unsigned short ushort_t;
typedef __bf16 bf16x8 __attribute__((ext_vector_type(8)));
typedef float f32x4 __attribute__((ext_vector_type(4)));
typedef unsigned short u16x8 __attribute__((ext_vector_type(8)));
typedef short s16x8 __attribute__((ext_vector_type(8)));

__device__ __forceinline__ ushort_t f2bf(float f) {
    unsigned u = __builtin_bit_cast(unsigned, f);
    unsigned r = (u + 0x7FFFu + ((u >> 16) & 1u)) >> 16;
    return (ushort_t)r;
}
__device__ __forceinline__ float bf2f(ushort_t h) {
    unsigned u = ((unsigned)h) << 16;
    return __builtin_bit_cast(float, u);
}

// ---------------------------------------------------------------------------
// Kernel A: Hilbert -> unit-phasor z, one block per (b,c) row.
// ---------------------------------------------------------------------------
#define FFT_N 2048
__device__ __forceinline__ int PADi(int i) { return i + (i >> 4); }

__device__ __forceinline__ void fft_dit_2048(float2* c, const float2* tw, int tid) {
#pragma unroll
    for (int s = 1; s <= 9; s += 2) {   // combined radix-4 (stages s, s+1)
        __syncthreads();
        const int q = 1 << (s - 1);
#pragma unroll
        for (int kk = 0; kk < 2; ++kk) {
            int k = tid + kk * 256;     // 512 butterflies
            int p = k & (q - 1);
            int g = k >> (s - 1);
            int i0 = (g << (s + 1)) + p;
            float2 a  = c[PADi(i0)];
            float2 bb = c[PADi(i0 + q)];
            float2 cc = c[PADi(i0 + 2 * q)];
            float2 dd = c[PADi(i0 + 3 * q)];
            float2 w1 = tw[PADi(p << (11 - s))];
            float2 w2 = tw[PADi(p << (10 - s))];
            float w3r = w1.x * w2.x - w1.y * w2.y;
            float w3i = w1.x * w2.y + w1.y * w2.x;
            float t1r = w1.x * bb.x - w1.y * bb.y, t1i = w1.x * bb.y + w1.y * bb.x;
            float t2r = w2.x * cc.x - w2.y * cc.y, t2i = w2.x * cc.y + w2.y * cc.x;
            float t3r = w3r * dd.x - w3i * dd.y,  t3i = w3r * dd.y + w3i * dd.x;
            float sAr = a.x + t1r, sAi = a.y + t1i;
            float sBr = a.x - t1r, sBi = a.y - t1i;
            float sCr = t2r + t3r, sCi = t2i + t3i;
            float uR  = t2r - t3r, uI  = t2i - t3i;
            c[PADi(i0)]         = make_float2(sAr + sCr, sAi + sCi);
            c[PADi(i0 + q)]     = make_float2(sBr + uI,  sBi - uR);
            c[PADi(i0 + 2 * q)] = make_float2(sAr - sCr, sAi - sCi);
            c[PADi(i0 + 3 * q)] = make_float2(sBr - uI,  sBi + uR);
        }
    }
    __syncthreads();
#pragma unroll
    for (int kk = 0; kk < 4; ++kk) {    // final radix-2 stage
        int k = tid + kk * 256;
        float2 w = tw[PADi(k)];
        float2 a = c[PADi(k)];
        float2 b = c[PADi(k + 1024)];
        float tr = w.x * b.x - w.y * b.y;
        float ti = w.x * b.y + w.y * b.x;
        c[PADi(k)]        = make_float2(a.x + tr, a.y + ti);
        c[PADi(k + 1024)] = make_float2(a.x - tr, a.y - ti);
    }
}

__global__ __launch_bounds__(256) void hilbert_kernel(
    const float* __restrict__ x, ushort_t* __restrict__ zre,
    ushort_t* __restrict__ zim, int b0)
{
    __shared__ float2 c[2176];
    __shared__ float2 tw[1088];
    const int tid = threadIdx.x;
    const int row = blockIdx.x;
    const size_t grow = (size_t)(b0 * 128) + row;
    const float* xr = x + grow * FFT_N;

    for (int k = tid; k < 1024; k += 256) {
        float ang = -3.14159265358979323846f * (float)k / 1024.0f;
        float s, co;
        __sincosf(ang, &s, &co);
        tw[PADi(k)] = make_float2(co, s);
    }
    for (int i = tid; i < FFT_N; i += 256) {
        int j = __brev((unsigned)i) >> 21;
        c[PADi(j)] = make_float2(xr[i], 0.0f);
    }
    fft_dit_2048(c, tw, tid);
    __syncthreads();
    for (int i = tid; i < FFT_N; i += 256) {
        float f = (i == 0 || i == 1024) ? 1.0f : (i < 1024 ? 2.0f : 0.0f);
        float2 v = c[PADi(i)];
        c[PADi(i)] = make_float2(v.x * f, -v.y * f);
    }
    __syncthreads();
    for (int i = tid; i < FFT_N; i += 256) {
        int j = __brev((unsigned)i) >> 21;
        if (i < j) {
            float2 a = c[PADi(i)], b = c[PADi(j)];
            c[PADi(i)] = b;
            c[PADi(j)] = a;
        }
    }
    fft_dit_2048(c, tw, tid);
    __syncthreads();
    for (int n = tid; n < FFT_N; n += 256) {
        float2 w = c[PADi(n)];
        float m2 = w.x * w.x + w.y * w.y;
        float zr, zi;
        if (m2 < 1e-30f) { zr = 1.0f; zi = 0.0f; }
        else { float inv = rsqrtf(m2); zr = w.x * inv; zi = -w.y * inv; }
        zre[(size_t)row * FFT_N + n] = f2bf(zr);
        zim[(size_t)row * FFT_N + n] = f2bf(zi);
    }
}

// ---------------------------------------------------------------------------
// Kernel B: conn = |Z Z^H|/T (bf16 MFMA), unchanged from round 1.
// ---------------------------------------------------------------------------
__global__ __launch_bounds__(512) void gram_kernel(
    const ushort_t* __restrict__ zre, const ushort_t* __restrict__ zim,
    float* __restrict__ out, int b0)
{
    __shared__ __align__(16) char sm[65536];
    const int tid = threadIdx.x;
    const int bl = blockIdx.x;
    const int b_local = bl >> 1;
    const int half = bl & 1;
    const int b = b0 + b_local;
    const int lane = tid & 63;
    const int w = tid >> 6;
    const int wm = w >> 2, wn = w & 3;
    const size_t zbase = (size_t)b_local * 128 * FFT_N;

    f32x4 accR[2][2], accI[2][2];
    const f32x4 zero4 = {0.f, 0.f, 0.f, 0.f};
#pragma unroll
    for (int mi = 0; mi < 2; ++mi)
#pragma unroll
        for (int nj = 0; nj < 2; ++nj) { accR[mi][nj] = zero4; accI[mi][nj] = zero4; }

    auto stage = [&](int kc, int buf) {
        const int kcol = kc * 64;
#pragma unroll
        for (int it = 0; it < 4; ++it) {
            int cid = it * 512 + tid;
            int p = cid >> 10;
            int rem = cid & 1023;
            int r = rem >> 3;
            int g = rem & 7;
            const ushort_t* src = (p ? zim : zre) + zbase + (size_t)r * FFT_N + kcol + g * 8;
            u16x8 v = *(const u16x8*)src;
            int off = (buf << 15) | (p << 14) | (r << 7) | (g << 4);
            off ^= ((r & 7) << 4);
            *(u16x8*)(sm + off) = v;
        }
    };

    stage(0, 0);
    __syncthreads();
    int buf = 0;
    const int mBase = half * 64 + wm * 32;
    const int nBase = wn * 32;
    for (int kc = 0; kc < 32; ++kc) {
        if (kc + 1 < 32) stage(kc + 1, buf ^ 1);
        const char* base = sm + (buf << 15);
#pragma unroll
        for (int ks = 0; ks < 2; ++ks) {
            bf16x8 aRe[2], aIm[2], bRe[2], bIm[2], nRe[2];
#pragma unroll
            for (int mi = 0; mi < 2; ++mi) {
                int R = mBase + mi * 16 + (lane & 15);
                int off = (R << 7) | (ks << 6) | ((lane >> 4) << 4);
                off ^= ((R & 7) << 4);
                aRe[mi] = *(const bf16x8*)(base + off);
                aIm[mi] = *(const bf16x8*)(base + 16384 + off);
                s16x8 t = __builtin_bit_cast(s16x8, aRe[mi]);
                t ^= (short)0x8000;
                nRe[mi] = __builtin_bit_cast(bf16x8, t);
            }
#pragma unroll
            for (int nj = 0; nj < 2; ++nj) {
                int C = nBase + nj * 16 + (lane & 15);
                int off = (C << 7) | (ks << 6) | ((lane >> 4) << 4);
                off ^= ((C & 7) << 4);
                bRe[nj] = *(const bf16x8*)(base + off);
                bIm[nj] = *(const bf16x8*)(base + 16384 + off);
            }
#pragma unroll
            for (int mi = 0; mi < 2; ++mi)
#pragma unroll
                for (int nj = 0; nj < 2; ++nj) {
                    accR[mi][nj] = __builtin_amdgcn_mfma_f32_16x16x32_bf16(aRe[mi], bRe[nj], accR[mi][nj], 0, 0, 0);
                    accR[mi][nj] = __builtin_amdgcn_mfma_f32_16x16x32_bf16(aIm[mi], bIm[nj], accR[mi][nj], 0, 0, 0);
                    accI[mi][nj] = __builtin_amdgcn_mfma_f32_16x16x32_bf16(aIm[mi], bRe[nj], accI[mi][nj], 0, 0, 0);
                    accI[mi][nj] = __builtin_amdgcn_mfma_f32_16x16x32_bf16(nRe[mi], bIm[nj], accI[mi][nj], 0, 0, 0);
                }
        }
        __syncthreads();
        buf ^= 1;
    }
    float* ob = out + (size_t)b * 16384;
#pragma unroll
    for (int mi = 0; mi < 2; ++mi)
#pragma unroll
        for (int nj = 0; nj < 2; ++nj)
#pragma unroll
            for (int r = 0; r < 4; ++r) {
                int i = mBase + mi * 16 + (lane >> 4) * 4 + r;
                int j = nBase + nj * 16 + (lane & 15);
                float re = accR[mi][nj][r], im = accI[mi][nj][r];
                float v = sqrtf(re * re + im * im) * (1.0f / 2048.0f);
                if (i == j) v = 0.0f;
                ob[i * 128 + j] = v;
            }
}

// ---------------------------------------------------------------------------
// Kernel C (prep): nwT[f][j] = bf16(sum_e emb[j][e]*W1[e][f])  (128x128)
//                  w2t[f][g] = bf16(W2[g][f])                  (64x128)
// ---------------------------------------------------------------------------
__global__ __launch_bounds__(256) void prep_kernel(
    const float* __restrict__ emb, const float* __restrict__ W1,
    const float* __restrict__ W2, ushort_t* __restrict__ nwT,
    ushort_t* __restrict__ w2t)
{
    const int tid = threadIdx.x;
    const int bid = blockIdx.x;
    if (bid < 16) {
#pragma unroll
        for (int it = 0; it < 4; ++it) {
            int idx = it * 256 + tid;                 // 1024 per block
            int f = bid * 8 + (idx >> 7);
            int j = idx & 127;
            float acc = 0.0f;
            for (int e = 0; e < 64; ++e) acc += emb[j * 64 + e] * W1[e * 128 + f];
            nwT[f * 128 + j] = f2bf(acc);
        }
    } else {
        int base = (bid - 16) * 4096;
#pragma unroll
        for (int it = 0; it < 16; ++it) {
            int idx = base + it * 256 + tid;          // 8192 total
            int f = idx >> 7;
            int g = idx & 127;
            w2t[f * 128 + g] = f2bf(W2[g * 64 + f]);
        }
    }
}

// ---------------------------------------------------------------------------
// Kernel D1 (gcn_a): per (batch, half): 64 rows.
//   h1 = relu(conn @ nodeW1 + b1)  [MFMA, conn bf16 LDS, nwT B-frags global]
//   t2 = h1 @ W2                   [MFMA, h1 LDS, w2t B-frags global]
//   writes t2 transposed bf16: t2tg[b][f][jglob]
// ---------------------------------------------------------------------------
__global__ __launch_bounds__(512) void gcn_a(
    const float* __restrict__ conn, const ushort_t* __restrict__ nwT,
    const ushort_t* __restrict__ w2t, const float* __restrict__ b1,
    ushort_t* __restrict__ t2tg)
{
    __shared__ __align__(16) char cbf[16384];        // conn half rows, swizzled
    __shared__ __align__(16) char h1b[16384];        // h1 rows, swizzled
    const int tid = threadIdx.x;
    const int lane = tid & 63;
    const int w = tid >> 6;
    const int b = blockIdx.x >> 1;
    const int half = blockIdx.x & 1;
    const float* cb = conn + (size_t)b * 16384 + half * 64 * 128;

#pragma unroll
    for (int it = 0; it < 16; ++it) {                // stage conn -> bf16 LDS
        int idx = it * 512 + tid;                    // 8192
        int r = idx >> 7, cc = idx & 127;
        int off = (r * 256 + cc * 2) ^ ((r & 7) << 4);
        *(ushort_t*)(cbf + off) = f2bf(cb[idx]);
    }
    __syncthreads();

    // phase 1: wave wn = w, cols wn*16..+16; rows all 64 (4 frags)
    const int nBase = w * 16;
    f32x4 acc[4];
    const f32x4 zero4 = {0.f, 0.f, 0.f, 0.f};
#pragma unroll
    for (int mi = 0; mi < 4; ++mi) acc[mi] = zero4;
#pragma unroll
    for (int ks = 0; ks < 4; ++ks) {
        const bf16x8 bfrag = *(const bf16x8*)((const char*)nwT +
            (nBase + (lane & 15)) * 256 + ks * 64 + ((lane >> 4) << 4));
#pragma unroll
        for (int mi = 0; mi < 4; ++mi) {
            int R = mi * 16 + (lane & 15);
            int off = (R * 256 + ks * 64 + ((lane >> 4) << 4)) ^ ((R & 7) << 4);
            bf16x8 afrag = *(const bf16x8*)(cbf + off);
            acc[mi] = __builtin_amdgcn_mfma_f32_16x16x32_bf16(afrag, bfrag, acc[mi], 0, 0, 0);
        }
    }
    float bias1 = b1[nBase + (lane & 15)];
#pragma unroll
    for (int mi = 0; mi < 4; ++mi)
#pragma unroll
        for (int r = 0; r < 4; ++r) {
            int i = mi * 16 + (lane >> 4) * 4 + r;
            float v = fmaxf(acc[mi][r] + bias1, 0.0f);
            int off = (i * 256 + (nBase + (lane & 15)) * 2) ^ ((i & 7) << 4);
            *(ushort_t*)(h1b + off) = f2bf(v);
        }
    __syncthreads();

    // phase 2: t2 = h1 @ W2. waves (wm2=w>>2, wn2=w&3)
    const int wm2 = w >> 2, wn2 = w & 3;
    const int f2Base = wn2 * 16;
    f32x4 acc2[2];
    acc2[0] = zero4; acc2[1] = zero4;
#pragma unroll
    for (int ks = 0; ks < 4; ++ks) {
        const bf16x8 bfrag = *(const bf16x8*)((const char*)w2t +
            (f2Base + (lane & 15)) * 256 + ks * 64 + ((lane >> 4) << 4));
#pragma unroll
        for (int mi = 0; mi < 2; ++mi) {
            int R = wm2 * 32 + mi * 16 + (lane & 15);
            int off = (R * 256 + ks * 64 + ((lane >> 4) << 4)) ^ ((R & 7) << 4);
            bf16x8 afrag = *(const bf16x8*)(h1b + off);
            acc2[mi] = __builtin_amdgcn_mfma_f32_16x16x32_bf16(afrag, bfrag, acc2[mi], 0, 0, 0);
        }
    }
    ushort_t* tb = t2tg + (size_t)b * 8192;
#pragma unroll
    for (int mi = 0; mi < 2; ++mi)
#pragma unroll
        for (int r = 0; r < 4; ++r) {
            int i = wm2 * 32 + mi * 16 + (lane >> 4) * 4 + r;   // local row
            int f = f2Base + (lane & 15);
            tb[f * 128 + half * 64 + i] = f2bf(acc2[mi][r]);
        }
}

// ---------------------------------------------------------------------------
// Kernel D2 (gcn_b): h2 = conn @ t2 + b2  (B-frags from t2tg, f32 out)
// ---------------------------------------------------------------------------
__global__ __launch_bounds__(512) void gcn_b(
    const float* __restrict__ conn, const ushort_t* __restrict__ t2tg,
    const float* __restrict__ b2, float* __restrict__ h2out)
{
    __shared__ __align__(16) char cbf[16384];
    const int tid = threadIdx.x;
    const int lane = tid & 63;
    const int w = tid >> 6;
    const int b = blockIdx.x >> 1;
    const int half = blockIdx.x & 1;
    const float* cb = conn + (size_t)b * 16384 + half * 64 * 128;

#pragma unroll
    for (int it = 0; it < 16; ++it) {
        int idx = it * 512 + tid;
        int r = idx >> 7, cc = idx & 127;
        int off = (r * 256 + cc * 2) ^ ((r & 7) << 4);
        *(ushort_t*)(cbf + off) = f2bf(cb[idx]);
    }
    __syncthreads();

    const int wm = w >> 2, wn = w & 3;
    const int fBase = wn * 16;
    f32x4 acc[2];
    const f32x4 zero4 = {0.f, 0.f, 0.f, 0.f};
    acc[0] = zero4; acc[1] = zero4;
    const char* tbase = (const char*)t2tg + (size_t)b * 16384;
#pragma unroll
    for (int ks = 0; ks < 4; ++ks) {
        const bf16x8 bfrag = *(const bf16x8*)(tbase +
            (fBase + (lane & 15)) * 256 + ks * 64 + ((lane >> 4) << 4));
#pragma unroll
        for (int mi = 0; mi < 2; ++mi) {
            int R = wm * 32 + mi * 16 + (lane & 15);
            int off = (R * 256 + ks * 64 + ((lane >> 4) << 4)) ^ ((R & 7) << 4);
            bf16x8 afrag = *(const bf16x8*)(cbf + off);
            acc[mi] = __builtin_amdgcn_mfma_f32_16x16x32_bf16(afrag, bfrag, acc[mi], 0, 0, 0);
        }
    }
    float bias2 = b2[fBase + (lane & 15)];
    float* hb = h2out + (size_t)b * 8192;
#pragma unroll
    for (int mi = 0; mi < 2; ++mi)
#pragma unroll
        for (int r = 0; r < 4; ++r) {
            int i = half * 64 + wm * 32 + mi * 16 + (lane >> 4) * 4 + r;
            hb[i * 64 + fBase + (lane & 15)] = acc[mi][r] + bias2;
        }
}

// ---------------------------------------------------------------------------
// Kernel E: attention (round-1 version, sequential tasks, no spills)
// ---------------------------------------------------------------------------
__global__ __launch_bounds__(256) void attn_kernel(
    const float* __restrict__ h2, const float* __restrict__ Wq,
    const float* __restrict__ bq, const float* __restrict__ Wk,
    const float* __restrict__ bk, const float* __restrict__ Wv,
    const float* __restrict__ bv, const float* __restrict__ Wo,
    const float* __restrict__ bo, float* __restrict__ gf)
{
    __shared__ float h2T[64 * 130];
    __shared__ __align__(16) ushort_t kbf[128 * 64];
    __shared__ __align__(16) ushort_t vbf[128 * 64];
    __shared__ float osm[64 * 64];
    const int tid = threadIdx.x;
    const int b = blockIdx.x >> 1;
    const int half = blockIdx.x & 1;
    const float* h2b = h2 + (size_t)b * 8192;

    for (int idx = tid; idx < 8192; idx += 256) {
        int i = idx >> 6, e = idx & 63;
        h2T[e * 130 + i] = h2b[idx];
    }
    __syncthreads();
    for (int idx = tid; idx < 8192; idx += 256) {
        int i = idx >> 6, f = idx & 63;
        float ak = bk[f], av = bv[f];
        for (int e = 0; e < 64; ++e) {
            float h = h2T[e * 130 + i];
            ak += h * Wk[e * 64 + f];
            av += h * Wv[e * 64 + f];
        }
        kbf[idx] = f2bf(ak);
        vbf[idx] = f2bf(av);
    }
    __syncthreads();
    const float rs = 0.35355339059327373f;
    for (int it = 0; it < 2; ++it) {
        int task = tid + it * 256;
        int il = task & 63;
        int hb8 = (task >> 6) * 8;
        int i = half * 64 + il;
        float q[8];
#pragma unroll
        for (int d = 0; d < 8; ++d) q[d] = bq[hb8 + d];
        for (int e = 0; e < 64; ++e) {
            float hv = h2T[e * 130 + i];
            const float* wr = Wq + e * 64 + hb8;
#pragma unroll
            for (int d = 0; d < 8; ++d) q[d] += hv * wr[d];
        }
        float m = -3.0e38f, l = 0.0f;
        float o[8] = {0, 0, 0, 0, 0, 0, 0, 0};
        for (int j = 0; j < 128; ++j) {
            u16x8 kv = *(const u16x8*)(kbf + j * 64 + hb8);
            float s = 0.0f;
#pragma unroll
            for (int d = 0; d < 8; ++d) s += q[d] * bf2f(kv[d]);
            s *= rs;
            float mn = fmaxf(m, s);
            float cold = __expf(m - mn);
            float ce = __expf(s - mn);
            l = l * cold + ce;
            u16x8 vv = *(const u16x8*)(vbf + j * 64 + hb8);
#pragma unroll
            for (int d = 0; d < 8; ++d) o[d] = o[d] * cold + ce * bf2f(vv[d]);
            m = mn;
        }
        float inv = 1.0f / l;
#pragma unroll
        for (int d = 0; d < 8; ++d) osm[il * 64 + hb8 + d] = o[d] * inv;
    }
    __syncthreads();
    for (int idx = tid; idx < 4096; idx += 256) {
        int il = idx >> 6, f = idx & 63;
        float acc = bo[f];
        const float* orow = osm + il * 64;
        for (int e = 0; e < 64; ++e) acc += orow[e] * Wo[e * 64 + f];
        gf[(size_t)b * 8192 + (size_t)(half * 64 + il) * 64 + f] = acc;
    }
}

// ---------------------------------------------------------------------------
extern "C" void kernel_launch(void* const* d_in, const int* in_sizes, int n_in,
                              void* d_out, int out_size, void* d_ws, size_t ws_size,
                              hipStream_t stream)
{
    (void)in_sizes; (void)n_in; (void)out_size;
    const float* x   = (const float*)d_in[0];
    const float* emb = (const float*)d_in[1];
    const float* W1  = (const float*)d_in[2];
    const float* b1  = (const float*)d_in[3];
    const float* W2  = (const float*)d_in[4];
    const float* b2  = (const float*)d_in[5];
    const float* Wq  = (const float*)d_in[6];
    const float* bq  = (const float*)d_in[7];
    const float* Wk  = (const float*)d_in[8];
    const float* bk  = (const float*)d_in[9];
    const float* Wv  = (const float*)d_in[10];
    const float* bv  = (const float*)d_in[11];
    const float* Wo  = (const float*)d_in[12];
    const float* bo  = (const float*)d_in[13];

    float* out  = (float*)d_out;
    float* conn = out;                    // 128*128*128
    float* gf   = out + 2097152;          // 128*128*64
    float* h2   = out + 3145728;          // 128*128*64

    char* ws = (char*)d_ws;
    ushort_t* nwT  = (ushort_t*)ws;                 // 32KB
    ushort_t* w2t  = (ushort_t*)(ws + 32768);       // 16KB
    ushort_t* t2tg = (ushort_t*)(ws + 49152);       // 2MB (128 x 64 x 128 bf16)
    char* zbase = ws + 49152 + 2097152;
    size_t reserved = 49152 + 2097152;
    size_t avail = (ws_size > reserved) ? (ws_size - reserved) : 0;
    int nb = (int)(avail / 1048576);      // 1MB of z (re+im bf16) per batch
    if (nb < 1) nb = 1;
    if (nb > 128) nb = 128;

    for (int b0 = 0; b0 < 128; b0 += nb) {
        int cur = (nb < 128 - b0) ? nb : (128 - b0);
        ushort_t* zre = (ushort_t*)zbase;
        ushort_t* zim = zre + (size_t)cur * 128 * FFT_N;
        hilbert_kernel<<<cur * 128, 256, 0, stream>>>(x, zre, zim, b0);
        gram_kernel<<<cur * 2, 512, 0, stream>>>(zre, zim, conn, b0);
    }
    prep_kernel<<<18, 256, 0, stream>>>(emb, W1, W2, nwT, w2t);
    gcn_a<<<256, 512, 0, stream>>>(conn, nwT, w2t, b1, t2tg);
    gcn_b<<<256, 512, 0, stream>>>(conn, t2tg, b2, h2);
    attn_kernel<<<256, 256, 0, stream>>>(h2, Wq, bq, Wk, bk, Wv, bv, Wo, bo, gf);
}

// Round 4
// 339.806 us; speedup vs baseline: 2.9039x; 1.0779x over previous
//
#include <hip/hip_runtime.h>
#include <cstdint>
#include <cstddef>

typedef unsigned short ushort_t;
typedef __bf16 bf16x8 __attribute__((ext_vector_type(8)));
typedef float f32x4 __attribute__((ext_vector_type(4)));
typedef unsigned short u16x8 __attribute__((ext_vector_type(8)));
typedef short s16x8 __attribute__((ext_vector_type(8)));

__device__ __forceinline__ ushort_t f2bf(float f) {
    unsigned u = __builtin_bit_cast(unsigned, f);
    unsigned r = (u + 0x7FFFu + ((u >> 16) & 1u)) >> 16;
    return (ushort_t)r;
}
__device__ __forceinline__ float bf2f(ushort_t h) {
    unsigned u = ((unsigned)h) << 16;
    return __builtin_bit_cast(float, u);
}

// ---------------------------------------------------------------------------
// Kernel A: Hilbert -> unit-phasor z, one block per (b,c) row.
// Pipeline: load natural -> DIF fft (natural->bitrev) -> mask+conj in bitrev
// domain -> DIT fft (bitrev->natural) -> normalize+store. No bit-reverse
// data movement passes. Twiddles in per-level contiguous tables (stride-1 /
// broadcast reads, conflict-free); w1=w2^2, w3=w1*w2 in-register.
// ---------------------------------------------------------------------------
#define FFT_N 2048
__device__ __forceinline__ int PADi(int i) { return i + (i >> 4); }

// radix-4 DIT stage m (q=4^m): bitrev-input convention, verified r1-r3.
__device__ __forceinline__ void dit_r4_stage(float2* c, const float2* T, int m, int tid) {
    const int q = 1 << (2 * m);
    const float2* tb = T + ((q - 1) / 3);        // base (4^m-1)/3
#pragma unroll
    for (int kk = 0; kk < 2; ++kk) {
        int k = tid + kk * 256;
        int p = k & (q - 1);
        int g = k >> (2 * m);
        int i0 = g * (q << 2) + p;
        float2 a  = c[PADi(i0)];
        float2 bb = c[PADi(i0 + q)];
        float2 cc = c[PADi(i0 + 2 * q)];
        float2 dd = c[PADi(i0 + 3 * q)];
        float2 w2 = tb[p];                       // exp(-2pi i p / 2^(s+1))
        float w1r = w2.x * w2.x - w2.y * w2.y;   // w1 = w2^2
        float w1i = 2.0f * w2.x * w2.y;
        float w3r = w1r * w2.x - w1i * w2.y;     // w3 = w1*w2
        float w3i = w1r * w2.y + w1i * w2.x;
        float t1r = w1r * bb.x - w1i * bb.y, t1i = w1r * bb.y + w1i * bb.x;
        float t2r = w2.x * cc.x - w2.y * cc.y, t2i = w2.x * cc.y + w2.y * cc.x;
        float t3r = w3r * dd.x - w3i * dd.y,  t3i = w3r * dd.y + w3i * dd.x;
        float sAr = a.x + t1r, sAi = a.y + t1i;
        float sBr = a.x - t1r, sBi = a.y - t1i;
        float sCr = t2r + t3r, sCi = t2i + t3i;
        float uR  = t2r - t3r, uI  = t2i - t3i;
        c[PADi(i0)]         = make_float2(sAr + sCr, sAi + sCi);
        c[PADi(i0 + q)]     = make_float2(sBr + uI,  sBi - uR);
        c[PADi(i0 + 2 * q)] = make_float2(sAr - sCr, sAi - sCi);
        c[PADi(i0 + 3 * q)] = make_float2(sBr - uI,  sBi + uR);
    }
}

// radix-4 DIF stage m (q=4^m), block M=4q, w=exp(-2pi i/M); writes with
// branch 1<->2 swap so the final order is exact 11-bit bit-reversal.
__device__ __forceinline__ void dif_r4_stage(float2* c, const float2* T, int m, int tid) {
    const int q = 1 << (2 * m);
    const float2* tb = T + ((q - 1) / 3);
#pragma unroll
    for (int kk = 0; kk < 2; ++kk) {
        int k = tid + kk * 256;
        int n = k & (q - 1);
        int g = k >> (2 * m);
        int i0 = g * (q << 2) + n;
        float2 a  = c[PADi(i0)];
        float2 b  = c[PADi(i0 + q)];
        float2 cc = c[PADi(i0 + 2 * q)];
        float2 d  = c[PADi(i0 + 3 * q)];
        float2 wn = tb[n];                       // exp(-2pi i n / M)
        float w2r = wn.x * wn.x - wn.y * wn.y;   // wn^2
        float w2i = 2.0f * wn.x * wn.y;
        float w3r = w2r * wn.x - w2i * wn.y;     // wn^3
        float w3i = w2r * wn.y + w2i * wn.x;
        float t0r = a.x + cc.x, t0i = a.y + cc.y;
        float t1r = a.x - cc.x, t1i = a.y - cc.y;
        float t2r = b.x + d.x,  t2i = b.y + d.y;
        float t3r = b.x - d.x,  t3i = b.y - d.y;
        c[PADi(i0)] = make_float2(t0r + t2r, t0i + t2i);          // branch 0
        float cr = t0r - t2r, ci = t0i - t2i;                     // branch 2
        c[PADi(i0 + q)] = make_float2(cr * w2r - ci * w2i, cr * w2i + ci * w2r);
        float br = t1r + t3i, bi = t1i - t3r;                     // branch 1
        c[PADi(i0 + 2 * q)] = make_float2(br * wn.x - bi * wn.y, br * wn.y + bi * wn.x);
        float dr = t1r - t3i, di = t1i + t3r;                     // branch 3
        c[PADi(i0 + 3 * q)] = make_float2(dr * w3r - di * w3i, dr * w3i + di * w3r);
    }
}

__global__ __launch_bounds__(256) void hilbert_kernel(
    const float* __restrict__ x, ushort_t* __restrict__ zre,
    ushort_t* __restrict__ zim, int b0)
{
    __shared__ float2 c[2176];
    __shared__ float2 twl[341 + 1024];           // level tables + T11
    const int tid = threadIdx.x;
    const int row = blockIdx.x;
    const size_t grow = (size_t)(b0 * 128) + row;
    const float* xr = x + grow * FFT_N;
    const float2* T   = twl;
    const float2* T11 = twl + 341;

    for (int idx = tid; idx < 1365; idx += 256) {
        float ang;
        if (idx < 341) {                         // T_L[p], L=2m+2, size 4^m
            int m, p;
            if (idx >= 85)      { m = 4; p = idx - 85; }
            else if (idx >= 21) { m = 3; p = idx - 21; }
            else if (idx >= 5)  { m = 2; p = idx - 5; }
            else if (idx >= 1)  { m = 1; p = idx - 1; }
            else                { m = 0; p = 0; }
            ang = -6.28318530717958647692f * (float)p / (float)(4 << (2 * m));
        } else {                                 // T11[k] = exp(-i pi k/1024)
            ang = -3.14159265358979323846f * (float)(idx - 341) / 1024.0f;
        }
        float s, co;
        __sincosf(ang, &s, &co);
        twl[idx] = make_float2(co, s);
    }
    for (int i = tid; i < FFT_N; i += 256)       // natural-order load
        c[PADi(i)] = make_float2(xr[i], 0.0f);
    __syncthreads();

    // ---- DIF: radix-2 (stride 1024) then radix-4 m=4..0 ----
#pragma unroll
    for (int kk = 0; kk < 4; ++kk) {
        int n = tid + kk * 256;
        float2 a = c[PADi(n)], b = c[PADi(n + 1024)];
        float2 w = T11[n];
        float xr2 = a.x - b.x, xi2 = a.y - b.y;
        c[PADi(n)]        = make_float2(a.x + b.x, a.y + b.y);
        c[PADi(n + 1024)] = make_float2(xr2 * w.x - xi2 * w.y, xr2 * w.y + xi2 * w.x);
    }
#pragma unroll
    for (int m = 4; m >= 0; --m) {
        __syncthreads();
        dif_r4_stage(c, T, m, tid);
    }
    __syncthreads();

    // ---- mask + conj in bit-reversed domain ----
    for (int i = tid; i < FFT_N; i += 256) {
        int k = __brev((unsigned)i) >> 21;
        float f = (k == 0 || k == 1024) ? 1.0f : (k < 1024 ? 2.0f : 0.0f);
        float2 v = c[PADi(i)];
        c[PADi(i)] = make_float2(v.x * f, -v.y * f);
    }

    // ---- DIT: radix-4 m=0..4 then radix-2 (stride 1024) ----
#pragma unroll
    for (int m = 0; m <= 4; ++m) {
        __syncthreads();
        dit_r4_stage(c, T, m, tid);
    }
    __syncthreads();
#pragma unroll
    for (int kk = 0; kk < 4; ++kk) {
        int k = tid + kk * 256;
        float2 w = T11[k];
        float2 a = c[PADi(k)], b = c[PADi(k + 1024)];
        float tr = w.x * b.x - w.y * b.y;
        float ti = w.x * b.y + w.y * b.x;
        c[PADi(k)]        = make_float2(a.x + tr, a.y + ti);
        c[PADi(k + 1024)] = make_float2(a.x - tr, a.y - ti);
    }
    __syncthreads();

    for (int n = tid; n < FFT_N; n += 256) {
        float2 w = c[PADi(n)];
        float m2 = w.x * w.x + w.y * w.y;
        float zr, zi;
        if (m2 < 1e-30f) { zr = 1.0f; zi = 0.0f; }
        else { float inv = rsqrtf(m2); zr = w.x * inv; zi = -w.y * inv; }
        zre[(size_t)row * FFT_N + n] = f2bf(zr);
        zim[(size_t)row * FFT_N + n] = f2bf(zi);
    }
}

// ---------------------------------------------------------------------------
// Kernel B: conn = |Z Z^H|/T (bf16 MFMA), unchanged.
// ---------------------------------------------------------------------------
__global__ __launch_bounds__(512) void gram_kernel(
    const ushort_t* __restrict__ zre, const ushort_t* __restrict__ zim,
    float* __restrict__ out, int b0)
{
    __shared__ __align__(16) char sm[65536];
    const int tid = threadIdx.x;
    const int bl = blockIdx.x;
    const int b_local = bl >> 1;
    const int half = bl & 1;
    const int b = b0 + b_local;
    const int lane = tid & 63;
    const int w = tid >> 6;
    const int wm = w >> 2, wn = w & 3;
    const size_t zbase = (size_t)b_local * 128 * FFT_N;

    f32x4 accR[2][2], accI[2][2];
    const f32x4 zero4 = {0.f, 0.f, 0.f, 0.f};
#pragma unroll
    for (int mi = 0; mi < 2; ++mi)
#pragma unroll
        for (int nj = 0; nj < 2; ++nj) { accR[mi][nj] = zero4; accI[mi][nj] = zero4; }

    auto stage = [&](int kc, int buf) {
        const int kcol = kc * 64;
#pragma unroll
        for (int it = 0; it < 4; ++it) {
            int cid = it * 512 + tid;
            int p = cid >> 10;
            int rem = cid & 1023;
            int r = rem >> 3;
            int g = rem & 7;
            const ushort_t* src = (p ? zim : zre) + zbase + (size_t)r * FFT_N + kcol + g * 8;
            u16x8 v = *(const u16x8*)src;
            int off = (buf << 15) | (p << 14) | (r << 7) | (g << 4);
            off ^= ((r & 7) << 4);
            *(u16x8*)(sm + off) = v;
        }
    };

    stage(0, 0);
    __syncthreads();
    int buf = 0;
    const int mBase = half * 64 + wm * 32;
    const int nBase = wn * 32;
    for (int kc = 0; kc < 32; ++kc) {
        if (kc + 1 < 32) stage(kc + 1, buf ^ 1);
        const char* base = sm + (buf << 15);
#pragma unroll
        for (int ks = 0; ks < 2; ++ks) {
            bf16x8 aRe[2], aIm[2], bRe[2], bIm[2], nRe[2];
#pragma unroll
            for (int mi = 0; mi < 2; ++mi) {
                int R = mBase + mi * 16 + (lane & 15);
                int off = (R << 7) | (ks << 6) | ((lane >> 4) << 4);
                off ^= ((R & 7) << 4);
                aRe[mi] = *(const bf16x8*)(base + off);
                aIm[mi] = *(const bf16x8*)(base + 16384 + off);
                s16x8 t = __builtin_bit_cast(s16x8, aRe[mi]);
                t ^= (short)0x8000;
                nRe[mi] = __builtin_bit_cast(bf16x8, t);
            }
#pragma unroll
            for (int nj = 0; nj < 2; ++nj) {
                int C = nBase + nj * 16 + (lane & 15);
                int off = (C << 7) | (ks << 6) | ((lane >> 4) << 4);
                off ^= ((C & 7) << 4);
                bRe[nj] = *(const bf16x8*)(base + off);
                bIm[nj] = *(const bf16x8*)(base + 16384 + off);
            }
#pragma unroll
            for (int mi = 0; mi < 2; ++mi)
#pragma unroll
                for (int nj = 0; nj < 2; ++nj) {
                    accR[mi][nj] = __builtin_amdgcn_mfma_f32_16x16x32_bf16(aRe[mi], bRe[nj], accR[mi][nj], 0, 0, 0);
                    accR[mi][nj] = __builtin_amdgcn_mfma_f32_16x16x32_bf16(aIm[mi], bIm[nj], accR[mi][nj], 0, 0, 0);
                    accI[mi][nj] = __builtin_amdgcn_mfma_f32_16x16x32_bf16(aIm[mi], bRe[nj], accI[mi][nj], 0, 0, 0);
                    accI[mi][nj] = __builtin_amdgcn_mfma_f32_16x16x32_bf16(nRe[mi], bIm[nj], accI[mi][nj], 0, 0, 0);
                }
        }
        __syncthreads();
        buf ^= 1;
    }
    float* ob = out + (size_t)b * 16384;
#pragma unroll
    for (int mi = 0; mi < 2; ++mi)
#pragma unroll
        for (int nj = 0; nj < 2; ++nj)
#pragma unroll
            for (int r = 0; r < 4; ++r) {
                int i = mBase + mi * 16 + (lane >> 4) * 4 + r;
                int j = nBase + nj * 16 + (lane & 15);
                float re = accR[mi][nj][r], im = accI[mi][nj][r];
                float v = sqrtf(re * re + im * im) * (1.0f / 2048.0f);
                if (i == j) v = 0.0f;
                ob[i * 128 + j] = v;
            }
}

// ---------------------------------------------------------------------------
// Kernel C (prep): nwT[f][j] = bf16(sum_e emb[j][e]*W1[e][f]); w2t = W2^T bf16
// ---------------------------------------------------------------------------
__global__ __launch_bounds__(256) void prep_kernel(
    const float* __restrict__ emb, const float* __restrict__ W1,
    const float* __restrict__ W2, ushort_t* __restrict__ nwT,
    ushort_t* __restrict__ w2t)
{
    const int tid = threadIdx.x;
    const int bid = blockIdx.x;
    if (bid < 16) {
#pragma unroll
        for (int it = 0; it < 4; ++it) {
            int idx = it * 256 + tid;
            int f = bid * 8 + (idx >> 7);
            int j = idx & 127;
            float acc = 0.0f;
            for (int e = 0; e < 64; ++e) acc += emb[j * 64 + e] * W1[e * 128 + f];
            nwT[f * 128 + j] = f2bf(acc);
        }
    } else {
        int base = (bid - 16) * 4096;
#pragma unroll
        for (int it = 0; it < 16; ++it) {
            int idx = base + it * 256 + tid;
            int f = idx >> 7;
            int g = idx & 127;
            w2t[f * 128 + g] = f2bf(W2[g * 64 + f]);
        }
    }
}

// ---------------------------------------------------------------------------
// Kernel D1 (gcn_a): h1 = relu(conn@nodeW1+b1); t2 = h1@W2 (transposed bf16 out)
// ---------------------------------------------------------------------------
__global__ __launch_bounds__(512) void gcn_a(
    const float* __restrict__ conn, const ushort_t* __restrict__ nwT,
    const ushort_t* __restrict__ w2t, const float* __restrict__ b1,
    ushort_t* __restrict__ t2tg)
{
    __shared__ __align__(16) char cbf[16384];
    __shared__ __align__(16) char h1b[16384];
    const int tid = threadIdx.x;
    const int lane = tid & 63;
    const int w = tid >> 6;
    const int b = blockIdx.x >> 1;
    const int half = blockIdx.x & 1;
    const float* cb = conn + (size_t)b * 16384 + half * 64 * 128;

#pragma unroll
    for (int it = 0; it < 16; ++it) {
        int idx = it * 512 + tid;
        int r = idx >> 7, cc = idx & 127;
        int off = (r * 256 + cc * 2) ^ ((r & 7) << 4);
        *(ushort_t*)(cbf + off) = f2bf(cb[idx]);
    }
    __syncthreads();

    const int nBase = w * 16;
    f32x4 acc[4];
    const f32x4 zero4 = {0.f, 0.f, 0.f, 0.f};
#pragma unroll
    for (int mi = 0; mi < 4; ++mi) acc[mi] = zero4;
#pragma unroll
    for (int ks = 0; ks < 4; ++ks) {
        const bf16x8 bfrag = *(const bf16x8*)((const char*)nwT +
            (nBase + (lane & 15)) * 256 + ks * 64 + ((lane >> 4) << 4));
#pragma unroll
        for (int mi = 0; mi < 4; ++mi) {
            int R = mi * 16 + (lane & 15);
            int off = (R * 256 + ks * 64 + ((lane >> 4) << 4)) ^ ((R & 7) << 4);
            bf16x8 afrag = *(const bf16x8*)(cbf + off);
            acc[mi] = __builtin_amdgcn_mfma_f32_16x16x32_bf16(afrag, bfrag, acc[mi], 0, 0, 0);
        }
    }
    float bias1 = b1[nBase + (lane & 15)];
#pragma unroll
    for (int mi = 0; mi < 4; ++mi)
#pragma unroll
        for (int r = 0; r < 4; ++r) {
            int i = mi * 16 + (lane >> 4) * 4 + r;
            float v = fmaxf(acc[mi][r] + bias1, 0.0f);
            int off = (i * 256 + (nBase + (lane & 15)) * 2) ^ ((i & 7) << 4);
            *(ushort_t*)(h1b + off) = f2bf(v);
        }
    __syncthreads();

    const int wm2 = w >> 2, wn2 = w & 3;
    const int f2Base = wn2 * 16;
    f32x4 acc2[2];
    acc2[0] = zero4; acc2[1] = zero4;
#pragma unroll
    for (int ks = 0; ks < 4; ++ks) {
        const bf16x8 bfrag = *(const bf16x8*)((const char*)w2t +
            (f2Base + (lane & 15)) * 256 + ks * 64 + ((lane >> 4) << 4));
#pragma unroll
        for (int mi = 0; mi < 2; ++mi) {
            int R = wm2 * 32 + mi * 16 + (lane & 15);
            int off = (R * 256 + ks * 64 + ((lane >> 4) << 4)) ^ ((R & 7) << 4);
            bf16x8 afrag = *(const bf16x8*)(h1b + off);
            acc2[mi] = __builtin_amdgcn_mfma_f32_16x16x32_bf16(afrag, bfrag, acc2[mi], 0, 0, 0);
        }
    }
    ushort_t* tb = t2tg + (size_t)b * 8192;
#pragma unroll
    for (int mi = 0; mi < 2; ++mi)
#pragma unroll
        for (int r = 0; r < 4; ++r) {
            int i = wm2 * 32 + mi * 16 + (lane >> 4) * 4 + r;
            int f = f2Base + (lane & 15);
            tb[f * 128 + half * 64 + i] = f2bf(acc2[mi][r]);
        }
}

// ---------------------------------------------------------------------------
// Kernel D2 (gcn_b): h2 = conn @ t2 + b2
// ---------------------------------------------------------------------------
__global__ __launch_bounds__(512) void gcn_b(
    const float* __restrict__ conn, const ushort_t* __restrict__ t2tg,
    const float* __restrict__ b2, float* __restrict__ h2out)
{
    __shared__ __align__(16) char cbf[16384];
    const int tid = threadIdx.x;
    const int lane = tid & 63;
    const int w = tid >> 6;
    const int b = blockIdx.x >> 1;
    const int half = blockIdx.x & 1;
    const float* cb = conn + (size_t)b * 16384 + half * 64 * 128;

#pragma unroll
    for (int it = 0; it < 16; ++it) {
        int idx = it * 512 + tid;
        int r = idx >> 7, cc = idx & 127;
        int off = (r * 256 + cc * 2) ^ ((r & 7) << 4);
        *(ushort_t*)(cbf + off) = f2bf(cb[idx]);
    }
    __syncthreads();

    const int wm = w >> 2, wn = w & 3;
    const int fBase = wn * 16;
    f32x4 acc[2];
    const f32x4 zero4 = {0.f, 0.f, 0.f, 0.f};
    acc[0] = zero4; acc[1] = zero4;
    const char* tbase = (const char*)t2tg + (size_t)b * 16384;
#pragma unroll
    for (int ks = 0; ks < 4; ++ks) {
        const bf16x8 bfrag = *(const bf16x8*)(tbase +
            (fBase + (lane & 15)) * 256 + ks * 64 + ((lane >> 4) << 4));
#pragma unroll
        for (int mi = 0; mi < 2; ++mi) {
            int R = wm * 32 + mi * 16 + (lane & 15);
            int off = (R * 256 + ks * 64 + ((lane >> 4) << 4)) ^ ((R & 7) << 4);
            bf16x8 afrag = *(const bf16x8*)(cbf + off);
            acc[mi] = __builtin_amdgcn_mfma_f32_16x16x32_bf16(afrag, bfrag, acc[mi], 0, 0, 0);
        }
    }
    float bias2 = b2[fBase + (lane & 15)];
    float* hb = h2out + (size_t)b * 8192;
#pragma unroll
    for (int mi = 0; mi < 2; ++mi)
#pragma unroll
        for (int r = 0; r < 4; ++r) {
            int i = half * 64 + wm * 32 + mi * 16 + (lane >> 4) * 4 + r;
            hb[i * 64 + fBase + (lane & 15)] = acc[mi][r] + bias2;
        }
}

// ---------------------------------------------------------------------------
// Kernel E: attention (sequential tasks, no spills)
// ---------------------------------------------------------------------------
__global__ __launch_bounds__(256) void attn_kernel(
    const float* __restrict__ h2, const float* __restrict__ Wq,
    const float* __restrict__ bq, const float* __restrict__ Wk,
    const float* __restrict__ bk, const float* __restrict__ Wv,
    const float* __restrict__ bv, const float* __restrict__ Wo,
    const float* __restrict__ bo, float* __restrict__ gf)
{
    __shared__ float h2T[64 * 130];
    __shared__ __align__(16) ushort_t kbf[128 * 64];
    __shared__ __align__(16) ushort_t vbf[128 * 64];
    __shared__ float osm[64 * 64];
    const int tid = threadIdx.x;
    const int b = blockIdx.x >> 1;
    const int half = blockIdx.x & 1;
    const float* h2b = h2 + (size_t)b * 8192;

    for (int idx = tid; idx < 8192; idx += 256) {
        int i = idx >> 6, e = idx & 63;
        h2T[e * 130 + i] = h2b[idx];
    }
    __syncthreads();
    for (int idx = tid; idx < 8192; idx += 256) {
        int i = idx >> 6, f = idx & 63;
        float ak = bk[f], av = bv[f];
        for (int e = 0; e < 64; ++e) {
            float h = h2T[e * 130 + i];
            ak += h * Wk[e * 64 + f];
            av += h * Wv[e * 64 + f];
        }
        kbf[idx] = f2bf(ak);
        vbf[idx] = f2bf(av);
    }
    __syncthreads();
    const float rs = 0.35355339059327373f;
    for (int it = 0; it < 2; ++it) {
        int task = tid + it * 256;
        int il = task & 63;
        int hb8 = (task >> 6) * 8;
        int i = half * 64 + il;
        float q[8];
#pragma unroll
        for (int d = 0; d < 8; ++d) q[d] = bq[hb8 + d];
        for (int e = 0; e < 64; ++e) {
            float hv = h2T[e * 130 + i];
            const float* wr = Wq + e * 64 + hb8;
#pragma unroll
            for (int d = 0; d < 8; ++d) q[d] += hv * wr[d];
        }
        float m = -3.0e38f, l = 0.0f;
        float o[8] = {0, 0, 0, 0, 0, 0, 0, 0};
        for (int j = 0; j < 128; ++j) {
            u16x8 kv = *(const u16x8*)(kbf + j * 64 + hb8);
            float s = 0.0f;
#pragma unroll
            for (int d = 0; d < 8; ++d) s += q[d] * bf2f(kv[d]);
            s *= rs;
            float mn = fmaxf(m, s);
            float cold = __expf(m - mn);
            float ce = __expf(s - mn);
            l = l * cold + ce;
            u16x8 vv = *(const u16x8*)(vbf + j * 64 + hb8);
#pragma unroll
            for (int d = 0; d < 8; ++d) o[d] = o[d] * cold + ce * bf2f(vv[d]);
            m = mn;
        }
        float inv = 1.0f / l;
#pragma unroll
        for (int d = 0; d < 8; ++d) osm[il * 64 + hb8 + d] = o[d] * inv;
    }
    __syncthreads();
    for (int idx = tid; idx < 4096; idx += 256) {
        int il = idx >> 6, f = idx & 63;
        float acc = bo[f];
        const float* orow = osm + il * 64;
        for (int e = 0; e < 64; ++e) acc += orow[e] * Wo[e * 64 + f];
        gf[(size_t)b * 8192 + (size_t)(half * 64 + il) * 64 + f] = acc;
    }
}

// ---------------------------------------------------------------------------
extern "C" void kernel_launch(void* const* d_in, const int* in_sizes, int n_in,
                              void* d_out, int out_size, void* d_ws, size_t ws_size,
                              hipStream_t stream)
{
    (void)in_sizes; (void)n_in; (void)out_size;
    const float* x   = (const float*)d_in[0];
    const float* emb = (const float*)d_in[1];
    const float* W1  = (const float*)d_in[2];
    const float* b1  = (const float*)d_in[3];
    const float* W2  = (const float*)d_in[4];
    const float* b2  = (const float*)d_in[5];
    const float* Wq  = (const float*)d_in[6];
    const float* bq  = (const float*)d_in[7];
    const float* Wk  = (const float*)d_in[8];
    const float* bk  = (const float*)d_in[9];
    const float* Wv  = (const float*)d_in[10];
    const float* bv  = (const float*)d_in[11];
    const float* Wo  = (const float*)d_in[12];
    const float* bo  = (const float*)d_in[13];

    float* out  = (float*)d_out;
    float* conn = out;                    // 128*128*128
    float* gf   = out + 2097152;          // 128*128*64
    float* h2   = out + 3145728;          // 128*128*64

    char* ws = (char*)d_ws;
    ushort_t* nwT  = (ushort_t*)ws;                 // 32KB
    ushort_t* w2t  = (ushort_t*)(ws + 32768);       // 16KB
    ushort_t* t2tg = (ushort_t*)(ws + 49152);       // 2MB
    char* zbase = ws + 49152 + 2097152;
    size_t reserved = 49152 + 2097152;
    size_t avail = (ws_size > reserved) ? (ws_size - reserved) : 0;
    int nb = (int)(avail / 1048576);
    if (nb < 1) nb = 1;
    if (nb > 128) nb = 128;

    for (int b0 = 0; b0 < 128; b0 += nb) {
        int cur = (nb < 128 - b0) ? nb : (128 - b0);
        ushort_t* zre = (ushort_t*)zbase;
        ushort_t* zim = zre + (size_t)cur * 128 * FFT_N;
        hilbert_kernel<<<cur * 128, 256, 0, stream>>>(x, zre, zim, b0);
        gram_kernel<<<cur * 2, 512, 0, stream>>>(zre, zim, conn, b0);
    }
    prep_kernel<<<18, 256, 0, stream>>>(emb, W1, W2, nwT, w2t);
    gcn_a<<<256, 512, 0, stream>>>(conn, nwT, w2t, b1, t2tg);
    gcn_b<<<256, 512, 0, stream>>>(conn, t2tg, b2, h2);
    attn_kernel<<<256, 256, 0, stream>>>(h2, Wq, bq, Wk, bk, Wv, bv, Wo, bo, gf);
}

// Round 5
// 252.988 us; speedup vs baseline: 3.9004x; 1.3432x over previous
//
#include <hip/hip_runtime.h>
#include <cstdint>
#include <cstddef>

typedef unsigned short ushort_t;
typedef __bf16 bf16x8 __attribute__((ext_vector_type(8)));
typedef float f32x4 __attribute__((ext_vector_type(4)));
typedef unsigned short u16x8 __attribute__((ext_vector_type(8)));
typedef short s16x8 __attribute__((ext_vector_type(8)));

__device__ __forceinline__ ushort_t f2bf(float f) {
    unsigned u = __builtin_bit_cast(unsigned, f);
    unsigned r = (u + 0x7FFFu + ((u >> 16) & 1u)) >> 16;
    return (ushort_t)r;
}
__device__ __forceinline__ float bf2f(ushort_t h) {
    unsigned u = ((unsigned)h) << 16;
    return __builtin_bit_cast(float, u);
}

// ---------------------------------------------------------------------------
// Kernel A: Hilbert -> unit-phasor z. 2 rows per block, 128 threads/row.
// Register-blocked FFT: stage pairs fused in regs, 3 LDS round-trips per
// direction. DIF (natural->bitrev) -> mask in bitrev domain -> DIT
// (bitrev->natural). Butterfly math identical to verified round-3 stages.
// ---------------------------------------------------------------------------
#define FFT_N 2048
__device__ __forceinline__ int PADi(int i) { return i + (i >> 4); }

__device__ __forceinline__ float2 cmul(float2 u, float2 w) {
    return make_float2(u.x * w.x - u.y * w.y, u.x * w.y + u.y * w.x);
}
__device__ __forceinline__ float2 cadd(float2 a, float2 b) { return make_float2(a.x + b.x, a.y + b.y); }
__device__ __forceinline__ float2 csub(float2 a, float2 b) { return make_float2(a.x - b.x, a.y - b.y); }

// DIF radix-4, w = exp(-2pi i p / M); slot placement with branch 1<->2 swap
// (slots get: b0, b2*w^2, b1*w, b3*w^3) -- verbatim from verified dif_r4_stage.
__device__ __forceinline__ void dif4(float2* v, float2 w) {
    float2 t0 = cadd(v[0], v[2]);
    float2 t1 = csub(v[0], v[2]);
    float2 t2 = cadd(v[1], v[3]);
    float2 t3 = csub(v[1], v[3]);
    float2 w2 = make_float2(w.x * w.x - w.y * w.y, 2.0f * w.x * w.y);
    float2 w3 = cmul(w2, w);
    v[0] = cadd(t0, t2);
    v[1] = cmul(csub(t0, t2), w2);
    float2 b1 = make_float2(t1.x + t3.y, t1.y - t3.x);
    v[2] = cmul(b1, w);
    float2 b3 = make_float2(t1.x - t3.y, t1.y + t3.x);
    v[3] = cmul(b3, w3);
}

// DIT radix-4, w = tb[p] = exp(-2pi i p / 4q); natural slot placement --
// verbatim from verified dit_r4_stage.
__device__ __forceinline__ void dit4(float2* v, float2 w) {
    float2 w1 = make_float2(w.x * w.x - w.y * w.y, 2.0f * w.x * w.y);
    float2 w3 = cmul(w1, w);
    float2 t1 = cmul(v[1], w1);
    float2 t2 = cmul(v[2], w);
    float2 t3 = cmul(v[3], w3);
    float2 sA = cadd(v[0], t1);
    float2 sB = csub(v[0], t1);
    float2 sC = cadd(t2, t3);
    float2 u  = csub(t2, t3);
    v[0] = cadd(sA, sC);
    v[1] = make_float2(sB.x + u.y, sB.y - u.x);
    v[2] = csub(sA, sC);
    v[3] = make_float2(sB.x - u.y, sB.y + u.x);
}

__global__ __launch_bounds__(256) void hilbert_kernel(
    const float* __restrict__ x, ushort_t* __restrict__ zre,
    ushort_t* __restrict__ zim, int b0)
{
    __shared__ float2 cA[2][2176];
    __shared__ float2 twl[341 + 1024];
    const int tid = threadIdx.x;
    const int rloc = tid >> 7;
    const int t = tid & 127;
    const int row = blockIdx.x * 2 + rloc;
    const size_t grow = (size_t)(b0 * 128) + row;
    float2* c = cA[rloc];
    const float2* T   = twl;
    const float2* T11 = twl + 341;
    const float2* tb1 = twl + 1;
    const float2* tb2 = twl + 5;
    const float2* tb3 = twl + 21;
    const float2* tb4 = twl + 85;

    for (int idx = tid; idx < 1365; idx += 256) {
        float ang;
        if (idx < 341) {                         // T_L[p], size 4^m at (4^m-1)/3
            int m, p;
            if (idx >= 85)      { m = 4; p = idx - 85; }
            else if (idx >= 21) { m = 3; p = idx - 21; }
            else if (idx >= 5)  { m = 2; p = idx - 5; }
            else if (idx >= 1)  { m = 1; p = idx - 1; }
            else                { m = 0; p = 0; }
            ang = -6.28318530717958647692f * (float)p / (float)(4 << (2 * m));
        } else {                                 // T11[k] = exp(-i pi k/1024)
            ang = -3.14159265358979323846f * (float)(idx - 341) / 1024.0f;
        }
        float s, co;
        __sincosf(ang, &s, &co);
        twl[idx] = make_float2(co, s);
    }
    __syncthreads();

    const float* xr = x + grow * FFT_N;

    // ---- DIF pass 1: global -> regs (r2 over c, then r4 m=4 over a) -> LDS
#pragma unroll
    for (int it = 0; it < 2; ++it) {
        int i = t + it * 128;                    // [0,256)
        float2 v[4][2];                          // [a][c]
#pragma unroll
        for (int a = 0; a < 4; ++a) {
            float x0 = xr[i + 256 * a];
            float x1 = xr[i + 256 * a + 1024];
            float2 w = T11[i + 256 * a];
            v[a][0] = make_float2(x0 + x1, 0.0f);
            float d = x0 - x1;
            v[a][1] = make_float2(d * w.x, d * w.y);
        }
        float2 w4 = tb4[i];
#pragma unroll
        for (int cc = 0; cc < 2; ++cc) {
            float2 u[4];
#pragma unroll
            for (int a = 0; a < 4; ++a) u[a] = v[a][cc];
            dif4(u, w4);
            int base = PADi(i) + 1088 * cc;
#pragma unroll
            for (int s = 0; s < 4; ++s) c[base + 272 * s] = u[s];
        }
    }
    __syncthreads();

    // ---- DIF pass 2: m=3 over b (tb3[p+16a]), then m=2 over a (tb2[p])
    {
        int p = t & 15, g = t >> 4;              // g in [0,8)
        int base = 272 * g + p;                  // PADi(256g+p)
        float2 v[4][4];                          // [a][b]
#pragma unroll
        for (int a = 0; a < 4; ++a)
#pragma unroll
            for (int b = 0; b < 4; ++b) v[a][b] = c[base + 17 * a + 68 * b];
#pragma unroll
        for (int a = 0; a < 4; ++a) {
            float2 u[4];
#pragma unroll
            for (int b = 0; b < 4; ++b) u[b] = v[a][b];
            dif4(u, tb3[p + 16 * a]);
#pragma unroll
            for (int b = 0; b < 4; ++b) v[a][b] = u[b];
        }
        float2 w2p = tb2[p];
#pragma unroll
        for (int b = 0; b < 4; ++b) {
            float2 u[4];
#pragma unroll
            for (int a = 0; a < 4; ++a) u[a] = v[a][b];
            dif4(u, w2p);
#pragma unroll
            for (int a = 0; a < 4; ++a) v[a][b] = u[a];
        }
#pragma unroll
        for (int a = 0; a < 4; ++a)
#pragma unroll
            for (int b = 0; b < 4; ++b) c[base + 17 * a + 68 * b] = v[a][b];
    }
    __syncthreads();

    // ---- DIF pass 3: m=1 over b (tb1[a]), m=0 over a (w=1); fused mask+conj
    {
        int g = t;                               // [0,128)
        int base = 17 * g;
        float2 v[4][4];                          // [b][a], idx = 16g+4b+a
#pragma unroll
        for (int b = 0; b < 4; ++b)
#pragma unroll
            for (int a = 0; a < 4; ++a) v[b][a] = c[base + 4 * b + a];
#pragma unroll
        for (int a = 0; a < 4; ++a) {
            float2 u[4];
#pragma unroll
            for (int b = 0; b < 4; ++b) u[b] = v[b][a];
            dif4(u, tb1[a]);
#pragma unroll
            for (int b = 0; b < 4; ++b) v[b][a] = u[b];
        }
        const float2 one = make_float2(1.0f, 0.0f);
#pragma unroll
        for (int b = 0; b < 4; ++b) dif4(v[b], one);
#pragma unroll
        for (int b = 0; b < 4; ++b)
#pragma unroll
            for (int a = 0; a < 4; ++a) {
                int idx = 16 * g + 4 * b + a;
                int k = __brev((unsigned)idx) >> 21;
                float f = (k == 0 || k == 1024) ? 1.0f : (k < 1024 ? 2.0f : 0.0f);
                float2 w = v[b][a];
                c[base + 4 * b + a] = make_float2(w.x * f, -w.y * f);
            }
    }
    __syncthreads();

    // ---- DIT pass 1: m=0 over a (w=1), m=1 over b (tb1[a])
    {
        int g = t;
        int base = 17 * g;
        float2 v[4][4];                          // [b][a]
#pragma unroll
        for (int b = 0; b < 4; ++b)
#pragma unroll
            for (int a = 0; a < 4; ++a) v[b][a] = c[base + 4 * b + a];
        const float2 one = make_float2(1.0f, 0.0f);
#pragma unroll
        for (int b = 0; b < 4; ++b) dit4(v[b], one);
#pragma unroll
        for (int a = 0; a < 4; ++a) {
            float2 u[4];
#pragma unroll
            for (int b = 0; b < 4; ++b) u[b] = v[b][a];
            dit4(u, tb1[a]);
#pragma unroll
            for (int b = 0; b < 4; ++b) v[b][a] = u[b];
        }
#pragma unroll
        for (int b = 0; b < 4; ++b)
#pragma unroll
            for (int a = 0; a < 4; ++a) c[base + 4 * b + a] = v[b][a];
    }
    __syncthreads();

    // ---- DIT pass 2: m=2 over a (tb2[p]), m=3 over b (tb3[p+16a])
    {
        int p = t & 15, g = t >> 4;
        int base = 272 * g + p;
        float2 v[4][4];                          // [a][b]
#pragma unroll
        for (int a = 0; a < 4; ++a)
#pragma unroll
            for (int b = 0; b < 4; ++b) v[a][b] = c[base + 17 * a + 68 * b];
        float2 w2p = tb2[p];
#pragma unroll
        for (int b = 0; b < 4; ++b) {
            float2 u[4];
#pragma unroll
            for (int a = 0; a < 4; ++a) u[a] = v[a][b];
            dit4(u, w2p);
#pragma unroll
            for (int a = 0; a < 4; ++a) v[a][b] = u[a];
        }
#pragma unroll
        for (int a = 0; a < 4; ++a) {
            float2 u[4];
#pragma unroll
            for (int b = 0; b < 4; ++b) u[b] = v[a][b];
            dit4(u, tb3[p + 16 * a]);
#pragma unroll
            for (int b = 0; b < 4; ++b) v[a][b] = u[b];
        }
#pragma unroll
        for (int a = 0; a < 4; ++a)
#pragma unroll
            for (int b = 0; b < 4; ++b) c[base + 17 * a + 68 * b] = v[a][b];
    }
    __syncthreads();

    // ---- DIT pass 3: m=4 over a (tb4[i]), r2 over c (T11[i+256a]);
    //      normalize + store direct to global
    ushort_t* zr_out = zre + (size_t)row * FFT_N;
    ushort_t* zi_out = zim + (size_t)row * FFT_N;
#pragma unroll
    for (int it = 0; it < 2; ++it) {
        int i = t + it * 128;
        float2 v[4][2];                          // [a][c]
#pragma unroll
        for (int cc = 0; cc < 2; ++cc) {
            int base = PADi(i) + 1088 * cc;
#pragma unroll
            for (int a = 0; a < 4; ++a) v[a][cc] = c[base + 272 * a];
        }
        float2 w4 = tb4[i];
#pragma unroll
        for (int cc = 0; cc < 2; ++cc) {
            float2 u[4];
#pragma unroll
            for (int a = 0; a < 4; ++a) u[a] = v[a][cc];
            dit4(u, w4);
#pragma unroll
            for (int a = 0; a < 4; ++a) v[a][cc] = u[a];
        }
#pragma unroll
        for (int a = 0; a < 4; ++a) {
            float2 wa = T11[i + 256 * a];
            float2 tt = cmul(v[a][1], wa);
            float2 e0 = cadd(v[a][0], tt);
            float2 e1 = csub(v[a][0], tt);
            int n0 = i + 256 * a;
#pragma unroll
            for (int h = 0; h < 2; ++h) {
                float2 w = h ? e1 : e0;
                int n = n0 + 1024 * h;
                float m2 = w.x * w.x + w.y * w.y;
                float zr, zi;
                if (m2 < 1e-30f) { zr = 1.0f; zi = 0.0f; }
                else { float inv = rsqrtf(m2); zr = w.x * inv; zi = -w.y * inv; }
                zr_out[n] = f2bf(zr);
                zi_out[n] = f2bf(zi);
            }
        }
    }
}

// ---------------------------------------------------------------------------
// Kernel B: conn = |Z Z^H|/T (bf16 MFMA), unchanged.
// ---------------------------------------------------------------------------
__global__ __launch_bounds__(512) void gram_kernel(
    const ushort_t* __restrict__ zre, const ushort_t* __restrict__ zim,
    float* __restrict__ out, int b0)
{
    __shared__ __align__(16) char sm[65536];
    const int tid = threadIdx.x;
    const int bl = blockIdx.x;
    const int b_local = bl >> 1;
    const int half = bl & 1;
    const int b = b0 + b_local;
    const int lane = tid & 63;
    const int w = tid >> 6;
    const int wm = w >> 2, wn = w & 3;
    const size_t zbase = (size_t)b_local * 128 * FFT_N;

    f32x4 accR[2][2], accI[2][2];
    const f32x4 zero4 = {0.f, 0.f, 0.f, 0.f};
#pragma unroll
    for (int mi = 0; mi < 2; ++mi)
#pragma unroll
        for (int nj = 0; nj < 2; ++nj) { accR[mi][nj] = zero4; accI[mi][nj] = zero4; }

    auto stage = [&](int kc, int buf) {
        const int kcol = kc * 64;
#pragma unroll
        for (int it = 0; it < 4; ++it) {
            int cid = it * 512 + tid;
            int p = cid >> 10;
            int rem = cid & 1023;
            int r = rem >> 3;
            int g = rem & 7;
            const ushort_t* src = (p ? zim : zre) + zbase + (size_t)r * FFT_N + kcol + g * 8;
            u16x8 v = *(const u16x8*)src;
            int off = (buf << 15) | (p << 14) | (r << 7) | (g << 4);
            off ^= ((r & 7) << 4);
            *(u16x8*)(sm + off) = v;
        }
    };

    stage(0, 0);
    __syncthreads();
    int buf = 0;
    const int mBase = half * 64 + wm * 32;
    const int nBase = wn * 32;
    for (int kc = 0; kc < 32; ++kc) {
        if (kc + 1 < 32) stage(kc + 1, buf ^ 1);
        const char* base = sm + (buf << 15);
#pragma unroll
        for (int ks = 0; ks < 2; ++ks) {
            bf16x8 aRe[2], aIm[2], bRe[2], bIm[2], nRe[2];
#pragma unroll
            for (int mi = 0; mi < 2; ++mi) {
                int R = mBase + mi * 16 + (lane & 15);
                int off = (R << 7) | (ks << 6) | ((lane >> 4) << 4);
                off ^= ((R & 7) << 4);
                aRe[mi] = *(const bf16x8*)(base + off);
                aIm[mi] = *(const bf16x8*)(base + 16384 + off);
                s16x8 t = __builtin_bit_cast(s16x8, aRe[mi]);
                t ^= (short)0x8000;
                nRe[mi] = __builtin_bit_cast(bf16x8, t);
            }
#pragma unroll
            for (int nj = 0; nj < 2; ++nj) {
                int C = nBase + nj * 16 + (lane & 15);
                int off = (C << 7) | (ks << 6) | ((lane >> 4) << 4);
                off ^= ((C & 7) << 4);
                bRe[nj] = *(const bf16x8*)(base + off);
                bIm[nj] = *(const bf16x8*)(base + 16384 + off);
            }
#pragma unroll
            for (int mi = 0; mi < 2; ++mi)
#pragma unroll
                for (int nj = 0; nj < 2; ++nj) {
                    accR[mi][nj] = __builtin_amdgcn_mfma_f32_16x16x32_bf16(aRe[mi], bRe[nj], accR[mi][nj], 0, 0, 0);
                    accR[mi][nj] = __builtin_amdgcn_mfma_f32_16x16x32_bf16(aIm[mi], bIm[nj], accR[mi][nj], 0, 0, 0);
                    accI[mi][nj] = __builtin_amdgcn_mfma_f32_16x16x32_bf16(aIm[mi], bRe[nj], accI[mi][nj], 0, 0, 0);
                    accI[mi][nj] = __builtin_amdgcn_mfma_f32_16x16x32_bf16(nRe[mi], bIm[nj], accI[mi][nj], 0, 0, 0);
                }
        }
        __syncthreads();
        buf ^= 1;
    }
    float* ob = out + (size_t)b * 16384;
#pragma unroll
    for (int mi = 0; mi < 2; ++mi)
#pragma unroll
        for (int nj = 0; nj < 2; ++nj)
#pragma unroll
            for (int r = 0; r < 4; ++r) {
                int i = mBase + mi * 16 + (lane >> 4) * 4 + r;
                int j = nBase + nj * 16 + (lane & 15);
                float re = accR[mi][nj][r], im = accI[mi][nj][r];
                float v = sqrtf(re * re + im * im) * (1.0f / 2048.0f);
                if (i == j) v = 0.0f;
                ob[i * 128 + j] = v;
            }
}

// ---------------------------------------------------------------------------
// Kernel C (prep): nwT[f][j] = bf16(sum_e emb[j][e]*W1[e][f]); w2t = W2^T bf16
// ---------------------------------------------------------------------------
__global__ __launch_bounds__(256) void prep_kernel(
    const float* __restrict__ emb, const float* __restrict__ W1,
    const float* __restrict__ W2, ushort_t* __restrict__ nwT,
    ushort_t* __restrict__ w2t)
{
    const int tid = threadIdx.x;
    const int bid = blockIdx.x;
    if (bid < 16) {
#pragma unroll
        for (int it = 0; it < 4; ++it) {
            int idx = it * 256 + tid;
            int f = bid * 8 + (idx >> 7);
            int j = idx & 127;
            float acc = 0.0f;
            for (int e = 0; e < 64; ++e) acc += emb[j * 64 + e] * W1[e * 128 + f];
            nwT[f * 128 + j] = f2bf(acc);
        }
    } else {
        int base = (bid - 16) * 4096;
#pragma unroll
        for (int it = 0; it < 16; ++it) {
            int idx = base + it * 256 + tid;
            int f = idx >> 7;
            int g = idx & 127;
            w2t[f * 128 + g] = f2bf(W2[g * 64 + f]);
        }
    }
}

// ---------------------------------------------------------------------------
// Kernel D1 (gcn_a): h1 = relu(conn@nodeW1+b1); t2 = h1@W2 (transposed bf16 out)
// ---------------------------------------------------------------------------
__global__ __launch_bounds__(512) void gcn_a(
    const float* __restrict__ conn, const ushort_t* __restrict__ nwT,
    const ushort_t* __restrict__ w2t, const float* __restrict__ b1,
    ushort_t* __restrict__ t2tg)
{
    __shared__ __align__(16) char cbf[16384];
    __shared__ __align__(16) char h1b[16384];
    const int tid = threadIdx.x;
    const int lane = tid & 63;
    const int w = tid >> 6;
    const int b = blockIdx.x >> 1;
    const int half = blockIdx.x & 1;
    const float* cb = conn + (size_t)b * 16384 + half * 64 * 128;

#pragma unroll
    for (int it = 0; it < 16; ++it) {
        int idx = it * 512 + tid;
        int r = idx >> 7, cc = idx & 127;
        int off = (r * 256 + cc * 2) ^ ((r & 7) << 4);
        *(ushort_t*)(cbf + off) = f2bf(cb[idx]);
    }
    __syncthreads();

    const int nBase = w * 16;
    f32x4 acc[4];
    const f32x4 zero4 = {0.f, 0.f, 0.f, 0.f};
#pragma unroll
    for (int mi = 0; mi < 4; ++mi) acc[mi] = zero4;
#pragma unroll
    for (int ks = 0; ks < 4; ++ks) {
        const bf16x8 bfrag = *(const bf16x8*)((const char*)nwT +
            (nBase + (lane & 15)) * 256 + ks * 64 + ((lane >> 4) << 4));
#pragma unroll
        for (int mi = 0; mi < 4; ++mi) {
            int R = mi * 16 + (lane & 15);
            int off = (R * 256 + ks * 64 + ((lane >> 4) << 4)) ^ ((R & 7) << 4);
            bf16x8 afrag = *(const bf16x8*)(cbf + off);
            acc[mi] = __builtin_amdgcn_mfma_f32_16x16x32_bf16(afrag, bfrag, acc[mi], 0, 0, 0);
        }
    }
    float bias1 = b1[nBase + (lane & 15)];
#pragma unroll
    for (int mi = 0; mi < 4; ++mi)
#pragma unroll
        for (int r = 0; r < 4; ++r) {
            int i = mi * 16 + (lane >> 4) * 4 + r;
            float v = fmaxf(acc[mi][r] + bias1, 0.0f);
            int off = (i * 256 + (nBase + (lane & 15)) * 2) ^ ((i & 7) << 4);
            *(ushort_t*)(h1b + off) = f2bf(v);
        }
    __syncthreads();

    const int wm2 = w >> 2, wn2 = w & 3;
    const int f2Base = wn2 * 16;
    f32x4 acc2[2];
    acc2[0] = zero4; acc2[1] = zero4;
#pragma unroll
    for (int ks = 0; ks < 4; ++ks) {
        const bf16x8 bfrag = *(const bf16x8*)((const char*)w2t +
            (f2Base + (lane & 15)) * 256 + ks * 64 + ((lane >> 4) << 4));
#pragma unroll
        for (int mi = 0; mi < 2; ++mi) {
            int R = wm2 * 32 + mi * 16 + (lane & 15);
            int off = (R * 256 + ks * 64 + ((lane >> 4) << 4)) ^ ((R & 7) << 4);
            bf16x8 afrag = *(const bf16x8*)(h1b + off);
            acc2[mi] = __builtin_amdgcn_mfma_f32_16x16x32_bf16(afrag, bfrag, acc2[mi], 0, 0, 0);
        }
    }
    ushort_t* tb = t2tg + (size_t)b * 8192;
#pragma unroll
    for (int mi = 0; mi < 2; ++mi)
#pragma unroll
        for (int r = 0; r < 4; ++r) {
            int i = wm2 * 32 + mi * 16 + (lane >> 4) * 4 + r;
            int f = f2Base + (lane & 15);
            tb[f * 128 + half * 64 + i] = f2bf(acc2[mi][r]);
        }
}

// ---------------------------------------------------------------------------
// Kernel D2 (gcn_b): h2 = conn @ t2 + b2
// ---------------------------------------------------------------------------
__global__ __launch_bounds__(512) void gcn_b(
    const float* __restrict__ conn, const ushort_t* __restrict__ t2tg,
    const float* __restrict__ b2, float* __restrict__ h2out)
{
    __shared__ __align__(16) char cbf[16384];
    const int tid = threadIdx.x;
    const int lane = tid & 63;
    const int w = tid >> 6;
    const int b = blockIdx.x >> 1;
    const int half = blockIdx.x & 1;
    const float* cb = conn + (size_t)b * 16384 + half * 64 * 128;

#pragma unroll
    for (int it = 0; it < 16; ++it) {
        int idx = it * 512 + tid;
        int r = idx >> 7, cc = idx & 127;
        int off = (r * 256 + cc * 2) ^ ((r & 7) << 4);
        *(ushort_t*)(cbf + off) = f2bf(cb[idx]);
    }
    __syncthreads();

    const int wm = w >> 2, wn = w & 3;
    const int fBase = wn * 16;
    f32x4 acc[2];
    const f32x4 zero4 = {0.f, 0.f, 0.f, 0.f};
    acc[0] = zero4; acc[1] = zero4;
    const char* tbase = (const char*)t2tg + (size_t)b * 16384;
#pragma unroll
    for (int ks = 0; ks < 4; ++ks) {
        const bf16x8 bfrag = *(const bf16x8*)(tbase +
            (fBase + (lane & 15)) * 256 + ks * 64 + ((lane >> 4) << 4));
#pragma unroll
        for (int mi = 0; mi < 2; ++mi) {
            int R = wm * 32 + mi * 16 + (lane & 15);
            int off = (R * 256 + ks * 64 + ((lane >> 4) << 4)) ^ ((R & 7) << 4);
            bf16x8 afrag = *(const bf16x8*)(cbf + off);
            acc[mi] = __builtin_amdgcn_mfma_f32_16x16x32_bf16(afrag, bfrag, acc[mi], 0, 0, 0);
        }
    }
    float bias2 = b2[fBase + (lane & 15)];
    float* hb = h2out + (size_t)b * 8192;
#pragma unroll
    for (int mi = 0; mi < 2; ++mi)
#pragma unroll
        for (int r = 0; r < 4; ++r) {
            int i = half * 64 + wm * 32 + mi * 16 + (lane >> 4) * 4 + r;
            hb[i * 64 + fBase + (lane & 15)] = acc[mi][r] + bias2;
        }
}

// ---------------------------------------------------------------------------
// Kernel E: attention (sequential tasks, no spills)
// ---------------------------------------------------------------------------
__global__ __launch_bounds__(256) void attn_kernel(
    const float* __restrict__ h2, const float* __restrict__ Wq,
    const float* __restrict__ bq, const float* __restrict__ Wk,
    const float* __restrict__ bk, const float* __restrict__ Wv,
    const float* __restrict__ bv, const float* __restrict__ Wo,
    const float* __restrict__ bo, float* __restrict__ gf)
{
    __shared__ float h2T[64 * 130];
    __shared__ __align__(16) ushort_t kbf[128 * 64];
    __shared__ __align__(16) ushort_t vbf[128 * 64];
    __shared__ float osm[64 * 64];
    const int tid = threadIdx.x;
    const int b = blockIdx.x >> 1;
    const int half = blockIdx.x & 1;
    const float* h2b = h2 + (size_t)b * 8192;

    for (int idx = tid; idx < 8192; idx += 256) {
        int i = idx >> 6, e = idx & 63;
        h2T[e * 130 + i] = h2b[idx];
    }
    __syncthreads();
    for (int idx = tid; idx < 8192; idx += 256) {
        int i = idx >> 6, f = idx & 63;
        float ak = bk[f], av = bv[f];
        for (int e = 0; e < 64; ++e) {
            float h = h2T[e * 130 + i];
            ak += h * Wk[e * 64 + f];
            av += h * Wv[e * 64 + f];
        }
        kbf[idx] = f2bf(ak);
        vbf[idx] = f2bf(av);
    }
    __syncthreads();
    const float rs = 0.35355339059327373f;
    for (int it = 0; it < 2; ++it) {
        int task = tid + it * 256;
        int il = task & 63;
        int hb8 = (task >> 6) * 8;
        int i = half * 64 + il;
        float q[8];
#pragma unroll
        for (int d = 0; d < 8; ++d) q[d] = bq[hb8 + d];
        for (int e = 0; e < 64; ++e) {
            float hv = h2T[e * 130 + i];
            const float* wr = Wq + e * 64 + hb8;
#pragma unroll
            for (int d = 0; d < 8; ++d) q[d] += hv * wr[d];
        }
        float m = -3.0e38f, l = 0.0f;
        float o[8] = {0, 0, 0, 0, 0, 0, 0, 0};
        for (int j = 0; j < 128; ++j) {
            u16x8 kv = *(const u16x8*)(kbf + j * 64 + hb8);
            float s = 0.0f;
#pragma unroll
            for (int d = 0; d < 8; ++d) s += q[d] * bf2f(kv[d]);
            s *= rs;
            float mn = fmaxf(m, s);
            float cold = __expf(m - mn);
            float ce = __expf(s - mn);
            l = l * cold + ce;
            u16x8 vv = *(const u16x8*)(vbf + j * 64 + hb8);
#pragma unroll
            for (int d = 0; d < 8; ++d) o[d] = o[d] * cold + ce * bf2f(vv[d]);
            m = mn;
        }
        float inv = 1.0f / l;
#pragma unroll
        for (int d = 0; d < 8; ++d) osm[il * 64 + hb8 + d] = o[d] * inv;
    }
    __syncthreads();
    for (int idx = tid; idx < 4096; idx += 256) {
        int il = idx >> 6, f = idx & 63;
        float acc = bo[f];
        const float* orow = osm + il * 64;
        for (int e = 0; e < 64; ++e) acc += orow[e] * Wo[e * 64 + f];
        gf[(size_t)b * 8192 + (size_t)(half * 64 + il) * 64 + f] = acc;
    }
}

// ---------------------------------------------------------------------------
extern "C" void kernel_launch(void* const* d_in, const int* in_sizes, int n_in,
                              void* d_out, int out_size, void* d_ws, size_t ws_size,
                              hipStream_t stream)
{
    (void)in_sizes; (void)n_in; (void)out_size;
    const float* x   = (const float*)d_in[0];
    const float* emb = (const float*)d_in[1];
    const float* W1  = (const float*)d_in[2];
    const float* b1  = (const float*)d_in[3];
    const float* W2  = (const float*)d_in[4];
    const float* b2  = (const float*)d_in[5];
    const float* Wq  = (const float*)d_in[6];
    const float* bq  = (const float*)d_in[7];
    const float* Wk  = (const float*)d_in[8];
    const float* bk  = (const float*)d_in[9];
    const float* Wv  = (const float*)d_in[10];
    const float* bv  = (const float*)d_in[11];
    const float* Wo  = (const float*)d_in[12];
    const float* bo  = (const float*)d_in[13];

    float* out  = (float*)d_out;
    float* conn = out;                    // 128*128*128
    float* gf   = out + 2097152;          // 128*128*64
    float* h2   = out + 3145728;          // 128*128*64

    char* ws = (char*)d_ws;
    ushort_t* nwT  = (ushort_t*)ws;                 // 32KB
    ushort_t* w2t  = (ushort_t*)(ws + 32768);       // 16KB
    ushort_t* t2tg = (ushort_t*)(ws + 49152);       // 2MB
    char* zbase = ws + 49152 + 2097152;
    size_t reserved = 49152 + 2097152;
    size_t avail = (ws_size > reserved) ? (ws_size - reserved) : 0;
    int nb = (int)(avail / 1048576);
    if (nb < 1) nb = 1;
    if (nb > 128) nb = 128;

    for (int b0 = 0; b0 < 128; b0 += nb) {
        int cur = (nb < 128 - b0) ? nb : (128 - b0);
        ushort_t* zre = (ushort_t*)zbase;
        ushort_t* zim = zre + (size_t)cur * 128 * FFT_N;
        hilbert_kernel<<<cur * 64, 256, 0, stream>>>(x, zre, zim, b0);
        gram_kernel<<<cur * 2, 512, 0, stream>>>(zre, zim, conn, b0);
    }
    prep_kernel<<<18, 256, 0, stream>>>(emb, W1, W2, nwT, w2t);
    gcn_a<<<256, 512, 0, stream>>>(conn, nwT, w2t, b1, t2tg);
    gcn_b<<<256, 512, 0, stream>>>(conn, t2tg, b2, h2);
    attn_kernel<<<256, 256, 0, stream>>>(h2, Wq, bq, Wk, bk, Wv, bv, Wo, bo, gf);
}